// Round 3
// baseline (1613.128 us; speedup 1.0000x reference)
//
#include <hip/hip_runtime.h>
#include <cstdint>
#include <cstddef>

#define DEPTH 6
#define NB    16
#define NSEQ  512
#define EMB   1024
#define NHEAD 16
#define HDIM  64
#define FFD   2048
#define NTOK  (NB * NSEQ)   // 8192

typedef unsigned short u16;
using bf16x8 = __attribute__((ext_vector_type(8))) __bf16;
using f32x4  = __attribute__((ext_vector_type(4))) float;
using u16x4  = __attribute__((ext_vector_type(4))) u16;

typedef __attribute__((address_space(1))) uint32_t* as1_u32p;
typedef __attribute__((address_space(3))) uint32_t* as3_u32p;
typedef __attribute__((address_space(3))) u16*      as3_u16p;

__device__ __forceinline__ u16 f2bf(float f) {
  union { float f; uint32_t u; } v; v.f = f;
  uint32_t u = v.u;
  return (u16)((u + 0x7FFFu + ((u >> 16) & 1u)) >> 16);
}

__device__ __forceinline__ void gload_lds16(const u16* g, u16* l) {
  void* gp = const_cast<u16*>(g);
  __builtin_amdgcn_global_load_lds((as1_u32p)gp, (as3_u32p)l, 16, 0, 0);
}

// Stage a 16KB tile (rows of ROWBYTES bytes) global->LDS, linear LDS dest,
// XOR-swizzled global source so that reads with byte^((row&7)<<4) are
// bank-conflict-free (rule #21). 256-thread version.
template<int ROWBYTES>
__device__ __forceinline__ void stage16k(const u16* g0, int ldk, u16* lds) {
  int t = threadIdx.x;
#pragma unroll
  for (int i = 0; i < 4; ++i) {
    int off = (i * 256 + t) * 16;          // LDS byte offset
    int row = off / ROWBYTES;
    int pc  = (off % ROWBYTES) >> 4;
    int lc  = pc ^ (row & 7);
    gload_lds16(g0 + (size_t)row * ldk + lc * 8, lds + (off >> 1));
  }
}

// ---------------- weight prep: fp32 [K][N] -> bf16 [N][K] (B^T layout) ----
__global__ __launch_bounds__(256)
void wprep_k(const float* __restrict__ W, u16* __restrict__ Wt,
             int K, int N, size_t inL, size_t outL, size_t outOff)
{
  int ntiles = N >> 6, ktiles = K >> 6;
  int bid = blockIdx.x;
  int l = bid / (ktiles * ntiles);
  int r = bid % (ktiles * ntiles);
  int kt = r / ntiles, nt = r % ntiles;
  const float* in = W + (size_t)l * inL + (size_t)(kt * 64) * N + nt * 64;
  u16* out = Wt + (size_t)l * outL + outOff + (size_t)(nt * 64) * K + kt * 64;
  __shared__ float tile[64][65];
  int t = threadIdx.x;
  int tr = t >> 4, tc = (t & 15) * 4;
#pragma unroll
  for (int i = 0; i < 4; ++i) {
    f32x4 v = *(const f32x4*)(in + (size_t)(tr + i * 16) * N + tc);
    tile[tr + i * 16][tc + 0] = v[0];
    tile[tr + i * 16][tc + 1] = v[1];
    tile[tr + i * 16][tc + 2] = v[2];
    tile[tr + i * 16][tc + 3] = v[3];
  }
  __syncthreads();
#pragma unroll
  for (int i = 0; i < 4; ++i) {
    int nr = tr + i * 16;
    u16x4 o;
    o[0] = f2bf(tile[tc + 0][nr]);
    o[1] = f2bf(tile[tc + 1][nr]);
    o[2] = f2bf(tile[tc + 2][nr]);
    o[3] = f2bf(tile[tc + 3][nr]);
    *(u16x4*)(out + (size_t)nr * K + tc) = o;
  }
}

// ---------------- embed: concat cls + pos add ------------------------------
__global__ __launch_bounds__(256)
void embed_k(const float* __restrict__ x, const float* __restrict__ cls,
             const float* __restrict__ pos, float* __restrict__ H)
{
  int row = blockIdx.x, t = threadIdx.x;
  int b_ = row >> 9, n = row & 511;
  int c = t * 4;
  f32x4 p = *(const f32x4*)(pos + (size_t)n * EMB + c);
  f32x4 s;
  if (n == 0) s = *(const f32x4*)(cls + c);
  else        s = *(const f32x4*)(x + ((size_t)b_ * 511 + (n - 1)) * EMB + c);
  f32x4 o = s + p;
  *(f32x4*)(H + (size_t)row * EMB + c) = o;
}

// ---------------- layernorm: fp32 h -> bf16 xn ----------------------------
__global__ __launch_bounds__(256)
void ln_k(const float* __restrict__ H, const float* __restrict__ g,
          const float* __restrict__ b, u16* __restrict__ out)
{
  int row = blockIdx.x, t = threadIdx.x;
  const float* hp = H + (size_t)row * EMB;
  f32x4 v = *(const f32x4*)(hp + t * 4);
  float s  = v[0] + v[1] + v[2] + v[3];
  float ss = v[0]*v[0] + v[1]*v[1] + v[2]*v[2] + v[3]*v[3];
#pragma unroll
  for (int m = 1; m <= 32; m <<= 1) { s += __shfl_xor(s, m); ss += __shfl_xor(ss, m); }
  __shared__ float red[8];
  if ((t & 63) == 0) { red[(t >> 6) * 2] = s; red[(t >> 6) * 2 + 1] = ss; }
  __syncthreads();
  float S  = red[0] + red[2] + red[4] + red[6];
  float SS = red[1] + red[3] + red[5] + red[7];
  float mean = S * (1.0f / EMB);
  float var  = SS * (1.0f / EMB) - mean * mean;
  float rs = rsqrtf(var + 1e-5f);
  f32x4 gg = *(const f32x4*)(g + t * 4);
  f32x4 bb = *(const f32x4*)(b + t * 4);
  u16x4 o;
#pragma unroll
  for (int i = 0; i < 4; ++i) o[i] = f2bf((v[i] - mean) * rs * gg[i] + bb[i]);
  *(u16x4*)(out + (size_t)row * EMB + t * 4) = o;
}

// ======================= 256x256 8-phase GEMM (T2+T3+T4+T5) ================
// C[8192][N] = A[8192][K] * Bt[N][K]^T.  512 thr = 8 waves (2M x 4N),
// BK=64, 2 K-tiles per iteration, counted vmcnt(4), LDS 128 KB.
// EPI: 0 = QKV scatter (q,k,vT bf16);  2 = +bias, exact GELU -> outB bf16.

__device__ __forceinline__ void stageA256(u16* dst, const u16* src, int K,
                                          int half, int t) {
#pragma unroll
  for (int i = 0; i < 2; ++i) {
    int off = (i * 512 + t) * 16;            // byte offset within 16KB half
    int chunk = off >> 13;                   // two 8KB chunks (wm row groups)
    int row_in = (off >> 7) & 63;
    int lc = ((off >> 4) & 7) ^ (row_in & 7);
    int grow = chunk * 128 + half * 64 + row_in;
    gload_lds16(src + (size_t)grow * K + lc * 8, dst + (off >> 1));
  }
}

__device__ __forceinline__ void stageB256(u16* dst, const u16* src, int K,
                                          int half, int t) {
#pragma unroll
  for (int i = 0; i < 2; ++i) {
    int off = (i * 512 + t) * 16;
    int blk = off >> 12;                     // four 4KB blocks (wn col groups)
    int row_in = (off >> 7) & 31;
    int lc = ((off >> 4) & 7) ^ (row_in & 7);
    int nrow = blk * 64 + half * 32 + row_in;
    gload_lds16(src + (size_t)nrow * K + lc * 8, dst + (off >> 1));
  }
}

#define DS_A(BUF, MH) do {                                                   \
  const char* _ba = (const char*)&smA[BUF][MH][wm][0];                       \
  _Pragma("unroll") for (int mf = 0; mf < 4; ++mf) {                         \
    int ri = mf * 16 + r0; int swz = (r0 & 7) << 4;                          \
    af[mf][0] = *(const bf16x8*)(_ba + ri * 128 + ((kk0 * 2) ^ swz));        \
    af[mf][1] = *(const bf16x8*)(_ba + ri * 128 + (((32 + kk0) * 2) ^ swz)); \
  } } while (0)

#define DS_B(BUF, NH) do {                                                   \
  const char* _bb = (const char*)&smB[BUF][NH][wn][0];                       \
  _Pragma("unroll") for (int nf = 0; nf < 2; ++nf) {                         \
    int ri = nf * 16 + r0; int swz = (r0 & 7) << 4;                          \
    bfr[nf][0] = *(const bf16x8*)(_bb + ri * 128 + ((kk0 * 2) ^ swz));       \
    bfr[nf][1] = *(const bf16x8*)(_bb + ri * 128 + (((32 + kk0) * 2) ^ swz));\
  } } while (0)

#define MFMA16(MH, NH) do {                                                  \
  __builtin_amdgcn_s_setprio(1);                                             \
  _Pragma("unroll") for (int ks = 0; ks < 2; ++ks)                           \
  _Pragma("unroll") for (int mf = 0; mf < 4; ++mf)                           \
  _Pragma("unroll") for (int nf = 0; nf < 2; ++nf)                           \
    acc[MH * 4 + mf][NH * 2 + nf] = __builtin_amdgcn_mfma_f32_16x16x32_bf16( \
        af[mf][ks], bfr[nf][ks], acc[MH * 4 + mf][NH * 2 + nf], 0, 0, 0);    \
  __builtin_amdgcn_s_setprio(0);                                             \
} while (0)

#define BAR()       __builtin_amdgcn_s_barrier()
#define WAIT_LGKM0() do { asm volatile("s_waitcnt lgkmcnt(0)" ::: "memory"); \
                          __builtin_amdgcn_sched_barrier(0); } while (0)
#define VMCNT4()    asm volatile("s_waitcnt vmcnt(4)" ::: "memory")

template<int EPI>
__global__ __launch_bounds__(512, 2)
void gemm256_k(const u16* __restrict__ A, const u16* __restrict__ Bt,
               int nbn, int K,
               const float* __restrict__ bias, u16* __restrict__ outB,
               u16* __restrict__ qo, u16* __restrict__ ko, u16* __restrict__ vto)
{
  __shared__ u16 smA[2][2][2][4096];   // [buf][half][chunk(wm)][64x64] 64KB
  __shared__ u16 smB[2][2][4][2048];   // [buf][half][blk(wn)][32x64]   64KB

  int cpx = gridDim.x >> 3;
  int logical = (blockIdx.x & 7) * cpx + (blockIdx.x >> 3);
  int bm = logical / nbn, bn = logical % nbn;
  int t = threadIdx.x, lane = t & 63, w = t >> 6;
  int wm = w >> 2, wn = w & 3;
  int r0 = lane & 15, hi = lane >> 4, kk0 = hi * 8;
  const u16* Ab = A  + (size_t)(bm * 256) * K;
  const u16* Bb = Bt + (size_t)(bn * 256) * K;
  int nkt = K >> 6, T = nkt >> 1;

  // prologue: tile0 fully + tile1's A0,B1 (steady-state phases 7,8)
  stageA256(&smA[0][0][0][0], Ab, K, 0, t);
  stageA256(&smA[0][1][0][0], Ab, K, 1, t);
  stageB256(&smB[0][0][0][0], Bb, K, 0, t);
  stageB256(&smB[0][1][0][0], Bb, K, 1, t);
  stageA256(&smA[1][0][0][0], Ab + 64, K, 0, t);
  stageB256(&smB[1][1][0][0], Bb + 64, K, 1, t);
  VMCNT4();
  BAR();

  const f32x4 vzero = {0.f, 0.f, 0.f, 0.f};
  f32x4 acc[8][4];
#pragma unroll
  for (int i = 0; i < 8; ++i)
#pragma unroll
    for (int j = 0; j < 4; ++j) acc[i][j] = vzero;

  bf16x8 af[4][2], bfr[2][2];

  for (int it = 0; it < T; ++it) {
    int k1 = 2 * it + 1;
    int k2 = 2 * it + 2; if (k2 > nkt - 1) k2 = nkt - 1;   // clamped (dead-slot
    int k3 = 2 * it + 3; if (k3 > nkt - 1) k3 = nkt - 1;   // garbage on last it)
    // phase 1: quad(0,0) of tile 2t  | stage A1(2t+1)
    DS_A(0, 0); DS_B(0, 0);
    stageA256(&smA[1][1][0][0], Ab + k1 * 64, K, 1, t);
    BAR(); WAIT_LGKM0(); MFMA16(0, 0); BAR();
    // phase 2: quad(0,1)             | stage B0(2t+1)
    DS_B(0, 1);
    stageB256(&smB[1][0][0][0], Bb + k1 * 64, K, 0, t);
    BAR(); WAIT_LGKM0(); MFMA16(0, 1); BAR();
    // phase 3: quad(1,1)             | stage A0(2t+2)
    DS_A(0, 1);
    stageA256(&smA[0][0][0][0], Ab + k2 * 64, K, 0, t);
    BAR(); WAIT_LGKM0(); MFMA16(1, 1); BAR();
    // phase 4: quad(1,0)             | stage B1(2t+2) | vmcnt(4)
    DS_B(0, 0);
    stageB256(&smB[0][1][0][0], Bb + k2 * 64, K, 1, t);
    VMCNT4();
    BAR(); WAIT_LGKM0(); MFMA16(1, 0); BAR();
    // phase 5: quad(0,0) of tile 2t+1| stage A1(2t+2)
    DS_A(1, 0); DS_B(1, 0);
    stageA256(&smA[0][1][0][0], Ab + k2 * 64, K, 1, t);
    BAR(); WAIT_LGKM0(); MFMA16(0, 0); BAR();
    // phase 6: quad(0,1)             | stage B0(2t+2)
    DS_B(1, 1);
    stageB256(&smB[0][0][0][0], Bb + k2 * 64, K, 0, t);
    BAR(); WAIT_LGKM0(); MFMA16(0, 1); BAR();
    // phase 7: quad(1,1)             | stage A0(2t+3)
    DS_A(1, 1);
    stageA256(&smA[1][0][0][0], Ab + k3 * 64, K, 0, t);
    BAR(); WAIT_LGKM0(); MFMA16(1, 1); BAR();
    // phase 8: quad(1,0)             | stage B1(2t+3) | vmcnt(4)
    DS_B(1, 0);
    stageB256(&smB[1][1][0][0], Bb + k3 * 64, K, 1, t);
    VMCNT4();
    BAR(); WAIT_LGKM0(); MFMA16(1, 0); BAR();
  }

  // epilogue
  int m0 = bm * 256 + wm * 128;
  int n0 = bn * 256 + wn * 64;
#pragma unroll
  for (int mi = 0; mi < 8; ++mi) {
#pragma unroll
    for (int ni = 0; ni < 4; ++ni) {
      int col  = n0 + ni * 16 + r0;
      int rowb = m0 + mi * 16 + hi * 4;
      if (EPI == 0) {
        int which = col >> 10, c = col & 1023;
        int hh = c >> 6, d = c & 63;
        int b_ = rowb >> 9, n_ = rowb & 511;
        size_t bh = (size_t)(b_ * NHEAD + hh);
        if (which == 2) {
          u16x4 o;
#pragma unroll
          for (int j = 0; j < 4; ++j) o[j] = f2bf(acc[mi][ni][j]);
          *(u16x4*)(vto + (bh * HDIM + d) * NSEQ + n_) = o;
        } else {
          u16* dst = (which == 0) ? qo : ko;
#pragma unroll
          for (int j = 0; j < 4; ++j)
            dst[(bh * NSEQ + n_ + j) * HDIM + d] = f2bf(acc[mi][ni][j]);
        }
      } else {
#pragma unroll
        for (int j = 0; j < 4; ++j) {
          float xg = acc[mi][ni][j] + bias[col];
          float ge = 0.5f * xg * (1.0f + erff(xg * 0.70710678118654752f));
          outB[(size_t)(rowb + j) * FFD + col] = f2bf(ge);
        }
      }
    }
  }
}

// ---------------- 128x128 GEMM (for N=1024: proj / FF2) -------------------
// EPI: 1=+resid->H(f32)  3=+bias+resid->H(f32)
template<int EPI>
__global__ __launch_bounds__(256, 2)
void gemm_k(const u16* __restrict__ A, const u16* __restrict__ Bt,
            int nbn, int K,
            const float* __restrict__ bias, float* __restrict__ H)
{
  __shared__ u16 sm[2][2][128 * 64];   // 64 KB, double buffered A/B tiles
  int cpx = gridDim.x >> 3;
  int logical = (blockIdx.x & 7) * cpx + (blockIdx.x >> 3);
  int bm = logical / nbn, bn = logical % nbn;
  int t = threadIdx.x, lane = t & 63, w = t >> 6;
  int wm = w >> 1, wn = w & 1;
  const u16* Ab = A  + (size_t)(bm * 128) * K;
  const u16* Bb = Bt + (size_t)(bn * 128) * K;
  int nkt = K >> 6;

  stage16k<128>(Ab, K, &sm[0][0][0]);
  stage16k<128>(Bb, K, &sm[0][1][0]);
  __syncthreads();

  const f32x4 vzero = {0.f, 0.f, 0.f, 0.f};
  f32x4 acc[4][4];
#pragma unroll
  for (int i = 0; i < 4; ++i)
#pragma unroll
    for (int j = 0; j < 4; ++j) acc[i][j] = vzero;

  int r0 = lane & 15;
  int kk0 = (lane >> 4) * 8;

  for (int kt = 0; kt < nkt; ++kt) {
    int cur = kt & 1;
    if (kt + 1 < nkt) {
      stage16k<128>(Ab + (kt + 1) * 64, K, &sm[cur ^ 1][0][0]);
      stage16k<128>(Bb + (kt + 1) * 64, K, &sm[cur ^ 1][1][0]);
    }
    const char* smAp = (const char*)&sm[cur][0][0];
    const char* smBp = (const char*)&sm[cur][1][0];
#pragma unroll
    for (int ks = 0; ks < 2; ++ks) {
      int kk = ks * 32 + kk0;
      bf16x8 a[4], b[4];
#pragma unroll
      for (int mf = 0; mf < 4; ++mf) {
        int row = wm * 64 + mf * 16 + r0;
        a[mf] = *(const bf16x8*)(smAp + row * 128 + ((kk * 2) ^ ((row & 7) << 4)));
      }
#pragma unroll
      for (int nf = 0; nf < 4; ++nf) {
        int row = wn * 64 + nf * 16 + r0;
        b[nf] = *(const bf16x8*)(smBp + row * 128 + ((kk * 2) ^ ((row & 7) << 4)));
      }
#pragma unroll
      for (int mf = 0; mf < 4; ++mf)
#pragma unroll
        for (int nf = 0; nf < 4; ++nf)
          acc[mf][nf] = __builtin_amdgcn_mfma_f32_16x16x32_bf16(a[mf], b[nf], acc[mf][nf], 0, 0, 0);
    }
    __syncthreads();
  }

  int m0 = bm * 128 + wm * 64;
  int n0 = bn * 128 + wn * 64;
  int hi = lane >> 4;
#pragma unroll
  for (int mf = 0; mf < 4; ++mf) {
#pragma unroll
    for (int nf = 0; nf < 4; ++nf) {
      int col  = n0 + nf * 16 + r0;
      int rowb = m0 + mf * 16 + hi * 4;
#pragma unroll
      for (int j = 0; j < 4; ++j) {
        int row = rowb + j;
        float v = acc[mf][nf][j];
        size_t idx = (size_t)row * EMB + col;
        if (EPI == 1) H[idx] = v + H[idx];
        else          H[idx] = v + bias[col] + H[idx];
      }
    }
  }
}

// ---------------- fused attention -----------------------------------------
__global__ __launch_bounds__(256, 3)
void attn_k(const u16* __restrict__ Q, const u16* __restrict__ Kk,
            const u16* __restrict__ Vt, u16* __restrict__ AO)
{
  __shared__ u16 kv[2][8192];      // 32 KB staging (K chunks, then V chunks)
  __shared__ u16 Pt[4][2048];      // 16 KB: per-wave P^T chunk [128k][16q]
  int bid = blockIdx.x;
  int bh = (bid & 7) * 32 + (bid >> 6);      // all 8 q-tiles of a bh -> one XCD
  int qt = (bid >> 3) & 7;
  int t = threadIdx.x, lane = t & 63, w = t >> 6;
  const u16* Kb = Kk + (size_t)bh * (NSEQ * HDIM);
  const u16* Vb = Vt + (size_t)bh * (HDIM * NSEQ);
  int r0 = lane & 15, hi = lane >> 4, kk0 = hi * 8;

  int qrow = qt * 64 + w * 16 + r0;
  const u16* Qp = Q + ((size_t)bh * NSEQ + qrow) * HDIM;
  bf16x8 qf0 = *(const bf16x8*)(Qp + kk0);
  bf16x8 qf1 = *(const bf16x8*)(Qp + 32 + kk0);

  const f32x4 vzero = {0.f, 0.f, 0.f, 0.f};
  f32x4 accS[32];
#pragma unroll
  for (int f = 0; f < 32; ++f) accS[f] = vzero;

  stage16k<128>(Kb, HDIM, &kv[0][0]);
  __syncthreads();
#pragma unroll
  for (int kt = 0; kt < 4; ++kt) {
    if (kt < 3) stage16k<128>(Kb + (size_t)(kt + 1) * 128 * HDIM, HDIM, &kv[(kt + 1) & 1][0]);
    const char* smK = (const char*)&kv[kt & 1][0];
#pragma unroll
    for (int nfl = 0; nfl < 8; ++nfl) {
      int krow = nfl * 16 + r0;
      int swz = (krow & 7) << 4;
      bf16x8 b0 = *(const bf16x8*)(smK + krow * 128 + (((kk0)      * 2) ^ swz));
      bf16x8 b1 = *(const bf16x8*)(smK + krow * 128 + (((32 + kk0) * 2) ^ swz));
      accS[kt * 8 + nfl] = __builtin_amdgcn_mfma_f32_16x16x32_bf16(qf0, b0, accS[kt * 8 + nfl], 0, 0, 0);
      accS[kt * 8 + nfl] = __builtin_amdgcn_mfma_f32_16x16x32_bf16(qf1, b1, accS[kt * 8 + nfl], 0, 0, 0);
    }
    __syncthreads();
  }

  stage16k<256>(Vb, NSEQ, &kv[0][0]);

  float mx[4], den[4], rden[4];
#pragma unroll
  for (int j = 0; j < 4; ++j) {
    float m = -1e30f;
#pragma unroll
    for (int f = 0; f < 32; ++f) m = fmaxf(m, accS[f][j]);
    m = fmaxf(m, __shfl_xor(m, 1));
    m = fmaxf(m, __shfl_xor(m, 2));
    m = fmaxf(m, __shfl_xor(m, 4));
    m = fmaxf(m, __shfl_xor(m, 8));
    mx[j] = m;
    den[j] = 0.f;
  }
  uint32_t pb[64];
#pragma unroll
  for (int f = 0; f < 32; ++f) {
    float p0 = __expf((accS[f][0] - mx[0]) * 0.03125f);
    float p1 = __expf((accS[f][1] - mx[1]) * 0.03125f);
    float p2 = __expf((accS[f][2] - mx[2]) * 0.03125f);
    float p3 = __expf((accS[f][3] - mx[3]) * 0.03125f);
    den[0] += p0; den[1] += p1; den[2] += p2; den[3] += p3;
    pb[f * 2 + 0] = (uint32_t)f2bf(p0) | ((uint32_t)f2bf(p1) << 16);
    pb[f * 2 + 1] = (uint32_t)f2bf(p2) | ((uint32_t)f2bf(p3) << 16);
  }
#pragma unroll
  for (int j = 0; j < 4; ++j) {
    float d = den[j];
    d += __shfl_xor(d, 1); d += __shfl_xor(d, 2);
    d += __shfl_xor(d, 4); d += __shfl_xor(d, 8);
    rden[j] = 1.0f / d;
  }
  __syncthreads();

  int perm0 = ((r0 & 4) << 2) + ((r0 >> 3) << 2) + (r0 & 3);
  uint32_t ptb = (uint32_t)(uintptr_t)(as3_u16p)&Pt[w][0];
  uint32_t trBase = ptb + r0 * 2 + hi * 128;
  char* PtW = (char*)&Pt[w][0];

  f32x4 accO[4];
#pragma unroll
  for (int nf = 0; nf < 4; ++nf) accO[nf] = vzero;

#pragma unroll
  for (int kt = 0; kt < 4; ++kt) {
    if (kt < 3) stage16k<256>(Vb + (kt + 1) * 128, NSEQ, &kv[(kt + 1) & 1][0]);
#pragma unroll
    for (int fl = 0; fl < 8; ++fl) {
      int f = kt * 8 + fl;
      int row = (fl >> 1) * 32 + perm0 + ((fl & 1) << 3);
      *(uint2*)(PtW + row * 32 + hi * 8) = make_uint2(pb[f * 2], pb[f * 2 + 1]);
    }
    asm volatile("s_waitcnt lgkmcnt(0)" ::: "memory");
    const char* smV = (const char*)&kv[kt & 1][0];
#pragma unroll
    for (int s = 0; s < 4; ++s) {
      uint2 t0, t1;
      uint32_t a0 = trBase + s * 1024;
      asm volatile("ds_read_b64_tr_b16 %0, %1" : "=v"(t0) : "v"(a0) : "memory");
      asm volatile("ds_read_b64_tr_b16 %0, %1" : "=v"(t1) : "v"(a0 + 512) : "memory");
      bf16x8 vb[4];
#pragma unroll
      for (int nf = 0; nf < 4; ++nf) {
        int d = nf * 16 + r0;
        int inrow = s * 64 + hi * 16;
        vb[nf] = *(const bf16x8*)(smV + d * 256 + (inrow ^ ((d & 7) << 4)));
      }
      asm volatile("s_waitcnt lgkmcnt(0)" ::: "memory");
      __builtin_amdgcn_sched_barrier(0);
      union { uint4 u; bf16x8 v; } pa;
      pa.u = make_uint4(t0.x, t0.y, t1.x, t1.y);
#pragma unroll
      for (int nf = 0; nf < 4; ++nf)
        accO[nf] = __builtin_amdgcn_mfma_f32_16x16x32_bf16(pa.v, vb[nf], accO[nf], 0, 0, 0);
    }
    __syncthreads();
  }

  int b_ = bh >> 4, hh = bh & 15;
#pragma unroll
  for (int nf = 0; nf < 4; ++nf)
#pragma unroll
    for (int j = 0; j < 4; ++j) {
      int ql = hi * 4 + j;
      int tok = qt * 64 + w * 16 + ql;
      int col = hh * 64 + nf * 16 + r0;
      AO[((size_t)(b_ * NSEQ + tok)) * EMB + col] = f2bf(accO[nf][j] * rden[j]);
    }
}

// ---------------- launch ---------------------------------------------------
extern "C" void kernel_launch(void* const* d_in, const int* in_sizes, int n_in,
                              void* d_out, int out_size, void* d_ws, size_t ws_size,
                              hipStream_t stream)
{
  const float* x    = (const float*)d_in[0];
  const float* cls  = (const float*)d_in[1];
  const float* pos  = (const float*)d_in[2];
  const float* Wq   = (const float*)d_in[3];
  const float* Wk   = (const float*)d_in[4];
  const float* Wv   = (const float*)d_in[5];
  const float* Wp   = (const float*)d_in[6];
  const float* ln1g = (const float*)d_in[7];
  const float* ln1b = (const float*)d_in[8];
  const float* ln2g = (const float*)d_in[9];
  const float* ln2b = (const float*)d_in[10];
  const float* W1   = (const float*)d_in[11];
  const float* b1   = (const float*)d_in[12];
  const float* W2   = (const float*)d_in[13];
  const float* b2   = (const float*)d_in[14];
  float* H = (float*)d_out;          // residual stream lives in d_out (fp32)

  char* ws = (char*)d_ws;            // 160 MiB used
  u16* wqkv = (u16*)(ws + 0);                // [6][3072][1024] bf16 (B^T)
  u16* wp   = (u16*)(ws + 37748736);         // [6][1024][1024]
  u16* w1t  = (u16*)(ws + 50331648);         // [6][2048][1024]
  u16* w2t  = (u16*)(ws + 75497472);         // [6][1024][2048]
  u16* xn   = (u16*)(ws + 100663296);        // [8192][1024] (also attn out)
  u16* qb   = (u16*)(ws + 117440512);        // [256][512][64]
  u16* kb   = (u16*)(ws + 134217728);        // [256][512][64]
  u16* vtb  = (u16*)(ws + 150994944);        // [256][64][512]
  u16* ffb  = qb;                            // [8192][2048] aliases q+k

  wprep_k<<<1536, 256, 0, stream>>>(Wq, wqkv, 1024, 1024, 1048576, 3145728, 0);
  wprep_k<<<1536, 256, 0, stream>>>(Wk, wqkv, 1024, 1024, 1048576, 3145728, 1048576);
  wprep_k<<<1536, 256, 0, stream>>>(Wv, wqkv, 1024, 1024, 1048576, 3145728, 2097152);
  wprep_k<<<1536, 256, 0, stream>>>(Wp, wp,   1024, 1024, 1048576, 1048576, 0);
  wprep_k<<<3072, 256, 0, stream>>>(W1, w1t,  1024, 2048, 2097152, 2097152, 0);
  wprep_k<<<3072, 256, 0, stream>>>(W2, w2t,  2048, 1024, 2097152, 2097152, 0);

  embed_k<<<NTOK, 256, 0, stream>>>(x, cls, pos, H);

  for (int l = 0; l < DEPTH; ++l) {
    ln_k<<<NTOK, 256, 0, stream>>>(H, ln1g + l * EMB, ln1b + l * EMB, xn);
    gemm256_k<0><<<384, 512, 0, stream>>>(xn, wqkv + (size_t)l * 3145728, 12, 1024,
                                          nullptr, nullptr, qb, kb, vtb);
    attn_k<<<2048, 256, 0, stream>>>(qb, kb, vtb, xn);
    gemm_k<1><<<512, 256, 0, stream>>>(xn, wp + (size_t)l * 1048576, 8, 1024,
                                       nullptr, H);
    ln_k<<<NTOK, 256, 0, stream>>>(H, ln2g + l * EMB, ln2b + l * EMB, xn);
    gemm256_k<2><<<256, 512, 0, stream>>>(xn, w1t + (size_t)l * 2097152, 8, 1024,
                                          b1 + l * FFD, ffb, nullptr, nullptr, nullptr);
    gemm_k<3><<<512, 256, 0, stream>>>(ffb, w2t + (size_t)l * 2097152, 8, 2048,
                                       b2 + l * EMB, H);
  }
}

// Round 4
// 1571.215 us; speedup vs baseline: 1.0267x; 1.0267x over previous
//
#include <hip/hip_runtime.h>
#include <cstdint>
#include <cstddef>

#define DEPTH 6
#define NB    16
#define NSEQ  512
#define EMB   1024
#define NHEAD 16
#define HDIM  64
#define FFD   2048
#define NTOK  (NB * NSEQ)   // 8192

typedef unsigned short u16;
using bf16x8 = __attribute__((ext_vector_type(8))) __bf16;
using f32x4  = __attribute__((ext_vector_type(4))) float;
using u16x4  = __attribute__((ext_vector_type(4))) u16;

typedef __attribute__((address_space(1))) uint32_t* as1_u32p;
typedef __attribute__((address_space(3))) uint32_t* as3_u32p;
typedef __attribute__((address_space(3))) u16*      as3_u16p;

__device__ __forceinline__ u16 f2bf(float f) {
  union { float f; uint32_t u; } v; v.f = f;
  uint32_t u = v.u;
  return (u16)((u + 0x7FFFu + ((u >> 16) & 1u)) >> 16);
}

__device__ __forceinline__ void gload_lds16(const u16* g, u16* l) {
  void* gp = const_cast<u16*>(g);
  __builtin_amdgcn_global_load_lds((as1_u32p)gp, (as3_u32p)l, 16, 0, 0);
}

// Stage a 16KB tile (rows of ROWBYTES bytes) global->LDS, linear LDS dest,
// XOR-swizzled global source so that reads with byte^((row&7)<<4) are
// bank-conflict-free (rule #21). 256-thread version.
template<int ROWBYTES>
__device__ __forceinline__ void stage16k(const u16* g0, int ldk, u16* lds) {
  int t = threadIdx.x;
#pragma unroll
  for (int i = 0; i < 4; ++i) {
    int off = (i * 256 + t) * 16;          // LDS byte offset
    int row = off / ROWBYTES;
    int pc  = (off % ROWBYTES) >> 4;
    int lc  = pc ^ (row & 7);
    gload_lds16(g0 + (size_t)row * ldk + lc * 8, lds + (off >> 1));
  }
}

// ---------------- weight prep: fp32 [K][N] -> bf16 [N][K] (B^T layout) ----
__global__ __launch_bounds__(256)
void wprep_k(const float* __restrict__ W, u16* __restrict__ Wt,
             int K, int N, size_t inL, size_t outL, size_t outOff)
{
  int ntiles = N >> 6, ktiles = K >> 6;
  int bid = blockIdx.x;
  int l = bid / (ktiles * ntiles);
  int r = bid % (ktiles * ntiles);
  int kt = r / ntiles, nt = r % ntiles;
  const float* in = W + (size_t)l * inL + (size_t)(kt * 64) * N + nt * 64;
  u16* out = Wt + (size_t)l * outL + outOff + (size_t)(nt * 64) * K + kt * 64;
  __shared__ float tile[64][65];
  int t = threadIdx.x;
  int tr = t >> 4, tc = (t & 15) * 4;
#pragma unroll
  for (int i = 0; i < 4; ++i) {
    f32x4 v = *(const f32x4*)(in + (size_t)(tr + i * 16) * N + tc);
    tile[tr + i * 16][tc + 0] = v[0];
    tile[tr + i * 16][tc + 1] = v[1];
    tile[tr + i * 16][tc + 2] = v[2];
    tile[tr + i * 16][tc + 3] = v[3];
  }
  __syncthreads();
#pragma unroll
  for (int i = 0; i < 4; ++i) {
    int nr = tr + i * 16;
    u16x4 o;
    o[0] = f2bf(tile[tc + 0][nr]);
    o[1] = f2bf(tile[tc + 1][nr]);
    o[2] = f2bf(tile[tc + 2][nr]);
    o[3] = f2bf(tile[tc + 3][nr]);
    *(u16x4*)(out + (size_t)nr * K + tc) = o;
  }
}

// ---------------- embed: concat cls + pos add ------------------------------
__global__ __launch_bounds__(256)
void embed_k(const float* __restrict__ x, const float* __restrict__ cls,
             const float* __restrict__ pos, float* __restrict__ H)
{
  int row = blockIdx.x, t = threadIdx.x;
  int b_ = row >> 9, n = row & 511;
  int c = t * 4;
  f32x4 p = *(const f32x4*)(pos + (size_t)n * EMB + c);
  f32x4 s;
  if (n == 0) s = *(const f32x4*)(cls + c);
  else        s = *(const f32x4*)(x + ((size_t)b_ * 511 + (n - 1)) * EMB + c);
  f32x4 o = s + p;
  *(f32x4*)(H + (size_t)row * EMB + c) = o;
}

// ---------------- layernorm: fp32 h -> bf16 xn ----------------------------
__global__ __launch_bounds__(256)
void ln_k(const float* __restrict__ H, const float* __restrict__ g,
          const float* __restrict__ b, u16* __restrict__ out)
{
  int row = blockIdx.x, t = threadIdx.x;
  const float* hp = H + (size_t)row * EMB;
  f32x4 v = *(const f32x4*)(hp + t * 4);
  float s  = v[0] + v[1] + v[2] + v[3];
  float ss = v[0]*v[0] + v[1]*v[1] + v[2]*v[2] + v[3]*v[3];
#pragma unroll
  for (int m = 1; m <= 32; m <<= 1) { s += __shfl_xor(s, m); ss += __shfl_xor(ss, m); }
  __shared__ float red[8];
  if ((t & 63) == 0) { red[(t >> 6) * 2] = s; red[(t >> 6) * 2 + 1] = ss; }
  __syncthreads();
  float S  = red[0] + red[2] + red[4] + red[6];
  float SS = red[1] + red[3] + red[5] + red[7];
  float mean = S * (1.0f / EMB);
  float var  = SS * (1.0f / EMB) - mean * mean;
  float rs = rsqrtf(var + 1e-5f);
  f32x4 gg = *(const f32x4*)(g + t * 4);
  f32x4 bb = *(const f32x4*)(b + t * 4);
  u16x4 o;
#pragma unroll
  for (int i = 0; i < 4; ++i) o[i] = f2bf((v[i] - mean) * rs * gg[i] + bb[i]);
  *(u16x4*)(out + (size_t)row * EMB + t * 4) = o;
}

// ======================= 256x256 8-phase GEMM, pipelined ====================
// One-phase-ahead register prefetch + counted lgkmcnt (T2+T3+T4+T5).
// 512 thr = 8 waves (2M x 4N), BK=64, 2 K-tiles/iter, vmcnt(4) at P4/P8.

__device__ __forceinline__ void stageA256(u16* dst, const u16* src, int K, int t) {
#pragma unroll
  for (int i = 0; i < 2; ++i) {
    int off = (i * 512 + t) * 16;            // byte offset within 16KB half
    int chunk = off >> 13;                   // two 8KB chunks (wm row groups)
    int row_in = (off >> 7) & 63;
    int lc = ((off >> 4) & 7) ^ (row_in & 7);
    gload_lds16(src + (size_t)(chunk * 128 + row_in) * K + lc * 8, dst + (off >> 1));
  }
}

__device__ __forceinline__ void stageB256(u16* dst, const u16* src, int K, int t) {
#pragma unroll
  for (int i = 0; i < 2; ++i) {
    int off = (i * 512 + t) * 16;
    int blk = off >> 12;                     // four 4KB blocks (wn col groups)
    int row_in = (off >> 7) & 31;
    int lc = ((off >> 4) & 7) ^ (row_in & 7);
    gload_lds16(src + (size_t)(blk * 64 + row_in) * K + lc * 8, dst + (off >> 1));
  }
}

#define RD_A(SET, BUF, MH) do {                                              \
  const char* _ba = (const char*)&smA[BUF][MH][wm][0];                       \
  _Pragma("unroll") for (int mf = 0; mf < 4; ++mf) {                         \
    int ri = mf * 16 + r0;                                                   \
    SET[mf][0] = *(const bf16x8*)(_ba + ri * 128 + ((kk0 * 2) ^ swz));       \
    SET[mf][1] = *(const bf16x8*)(_ba + ri * 128 + (((32 + kk0) * 2) ^ swz));\
  } } while (0)

#define RD_B(SET, BUF, NH) do {                                              \
  const char* _bb = (const char*)&smB[BUF][NH][wn][0];                       \
  _Pragma("unroll") for (int nf = 0; nf < 2; ++nf) {                         \
    int ri = nf * 16 + r0;                                                   \
    SET[nf][0] = *(const bf16x8*)(_bb + ri * 128 + ((kk0 * 2) ^ swz));       \
    SET[nf][1] = *(const bf16x8*)(_bb + ri * 128 + (((32 + kk0) * 2) ^ swz));\
  } } while (0)

#define MM(SA, SB, MH, NH) do {                                              \
  __builtin_amdgcn_s_setprio(1);                                             \
  _Pragma("unroll") for (int ks = 0; ks < 2; ++ks)                           \
  _Pragma("unroll") for (int mf = 0; mf < 4; ++mf)                           \
  _Pragma("unroll") for (int nf = 0; nf < 2; ++nf)                           \
    acc[MH * 4 + mf][NH * 2 + nf] = __builtin_amdgcn_mfma_f32_16x16x32_bf16( \
        SA[mf][ks], SB[nf][ks], acc[MH * 4 + mf][NH * 2 + nf], 0, 0, 0);     \
  __builtin_amdgcn_s_setprio(0);                                             \
} while (0)

#define BARR()   asm volatile("s_barrier" ::: "memory")
#define WAITC(N) do { asm volatile("s_waitcnt lgkmcnt(" #N ")" ::: "memory"); \
                      __builtin_amdgcn_sched_barrier(0); } while (0)
#define VM4()    asm volatile("s_waitcnt vmcnt(4)" ::: "memory")

template<int EPI>
__global__ __launch_bounds__(512, 2)
void gemm256_k(const u16* __restrict__ A, const u16* __restrict__ Bt,
               int nbn, int K,
               const float* __restrict__ bias, u16* __restrict__ outB,
               u16* __restrict__ qo, u16* __restrict__ ko, u16* __restrict__ vto)
{
  __shared__ u16 smA[2][2][2][4096];   // [buf][half][chunk(wm)][64x64] 64KB
  __shared__ u16 smB[2][2][4][2048];   // [buf][half][blk(wn)][32x64]   64KB

  int cpx = gridDim.x >> 3;
  int logical = (blockIdx.x & 7) * cpx + (blockIdx.x >> 3);
  int bm = logical / nbn, bn = logical % nbn;
  int t = threadIdx.x, lane = t & 63, w = t >> 6;
  int wm = w >> 2, wn = w & 3;
  int r0 = lane & 15, hi = lane >> 4, kk0 = hi * 8;
  int swz = (r0 & 7) << 4;
  const u16* Ab = A  + (size_t)(bm * 256) * K;
  const u16* Bb = Bt + (size_t)(bn * 256) * K;
  int nkt = K >> 6, T = nkt >> 1;

  // prologue: stage tiles 0 and 1 fully, then pre-read P1's registers
  stageA256(&smA[0][0][0][0], Ab + 0 * 64 + 0 * 64 * K, K, t);          // A00
  stageB256(&smB[0][0][0][0], Bb + 0 * 64 + 0 * 32 * K, K, t);          // B00
  stageB256(&smB[0][1][0][0], Bb + 0 * 64 + 32 * K, K, t);              // B01
  stageA256(&smA[0][1][0][0], Ab + 0 * 64 + 64 * K, K, t);              // A01
  stageA256(&smA[1][0][0][0], Ab + 1 * 64, K, t);                       // A10
  stageB256(&smB[1][0][0][0], Bb + 1 * 64, K, t);                       // B10
  stageB256(&smB[1][1][0][0], Bb + 1 * 64 + 32 * K, K, t);              // B11
  stageA256(&smA[1][1][0][0], Ab + 1 * 64 + 64 * K, K, t);              // A11
  asm volatile("s_waitcnt vmcnt(0)" ::: "memory");
  BARR();

  const f32x4 vzero = {0.f, 0.f, 0.f, 0.f};
  f32x4 acc[8][4];
#pragma unroll
  for (int i = 0; i < 8; ++i)
#pragma unroll
    for (int j = 0; j < 4; ++j) acc[i][j] = vzero;

  bf16x8 afA[4][2], afB[4][2], bfX[2][2], bfY[2][2];
  RD_A(afA, 0, 0);
  RD_B(bfX, 0, 0);

  for (int it = 0; it < T; ++it) {
    int k2 = 2 * it + 2; if (k2 >= nkt) k2 = nkt - 1;  // clamped tail stages
    int k3 = 2 * it + 3; if (k3 >= nkt) k3 = nkt - 1;
    // P1: quad(0,0) buf0 | prefetch B01 | stage A00(k2)
    RD_B(bfY, 0, 1);
    stageA256(&smA[0][0][0][0], Ab + k2 * 64 + 0 * K, K, t);
    WAITC(4); MM(afA, bfX, 0, 0); BARR();
    // P2: quad(0,1) | prefetch A01 | stage B00(k2)
    RD_A(afB, 0, 1);
    stageB256(&smB[0][0][0][0], Bb + k2 * 64 + 0 * K, K, t);
    WAITC(8); MM(afA, bfY, 0, 1); BARR();
    // P3: quad(1,1) | prefetch A10 | stage B01(k2)
    RD_A(afA, 1, 0);
    stageB256(&smB[0][1][0][0], Bb + k2 * 64 + 32 * K, K, t);
    WAITC(8); MM(afB, bfY, 1, 1); BARR();
    // P4: quad(1,0) | prefetch B10 | stage A01(k2) | vmcnt(4)
    RD_B(bfY, 1, 0);
    stageA256(&smA[0][1][0][0], Ab + k2 * 64 + 64 * K, K, t);
    VM4();
    WAITC(4); MM(afB, bfX, 1, 0); BARR();
    // P5: quad(0,0) buf1 | prefetch B11 | stage A10(k3)
    RD_B(bfX, 1, 1);
    stageA256(&smA[1][0][0][0], Ab + k3 * 64 + 0 * K, K, t);
    WAITC(4); MM(afA, bfY, 0, 0); BARR();
    // P6: quad(0,1) | prefetch A11 | stage B10(k3)
    RD_A(afB, 1, 1);
    stageB256(&smB[1][0][0][0], Bb + k3 * 64 + 0 * K, K, t);
    WAITC(8); MM(afA, bfX, 0, 1); BARR();
    // P7: quad(1,1) | prefetch A00(k2 tile) | stage B11(k3)
    RD_A(afA, 0, 0);
    stageB256(&smB[1][1][0][0], Bb + k3 * 64 + 32 * K, K, t);
    WAITC(8); MM(afB, bfX, 1, 1); BARR();
    // P8: quad(1,0) | prefetch B00(k2 tile) | stage A11(k3) | vmcnt(4)
    RD_B(bfX, 0, 0);
    stageA256(&smA[1][1][0][0], Ab + k3 * 64 + 64 * K, K, t);
    VM4();
    WAITC(4); MM(afB, bfY, 1, 0); BARR();
  }
  asm volatile("s_waitcnt vmcnt(0)" ::: "memory");

  // epilogue
  int m0 = bm * 256 + wm * 128;
  int n0 = bn * 256 + wn * 64;
#pragma unroll
  for (int mi = 0; mi < 8; ++mi) {
#pragma unroll
    for (int ni = 0; ni < 4; ++ni) {
      int col  = n0 + ni * 16 + r0;
      int rowb = m0 + mi * 16 + hi * 4;
      if (EPI == 0) {
        int which = col >> 10, c = col & 1023;
        int hh = c >> 6, d = c & 63;
        int b_ = rowb >> 9, n_ = rowb & 511;
        size_t bh = (size_t)(b_ * NHEAD + hh);
        if (which == 2) {
          u16x4 o;
#pragma unroll
          for (int j = 0; j < 4; ++j) o[j] = f2bf(acc[mi][ni][j]);
          *(u16x4*)(vto + (bh * HDIM + d) * NSEQ + n_) = o;
        } else {
          u16* dst = (which == 0) ? qo : ko;
#pragma unroll
          for (int j = 0; j < 4; ++j)
            dst[(bh * NSEQ + n_ + j) * HDIM + d] = f2bf(acc[mi][ni][j]);
        }
      } else {
#pragma unroll
        for (int j = 0; j < 4; ++j) {
          float xg = acc[mi][ni][j] + bias[col];
          float ge = 0.5f * xg * (1.0f + erff(xg * 0.70710678118654752f));
          outB[(size_t)(rowb + j) * FFD + col] = f2bf(ge);
        }
      }
    }
  }
}

// ---------------- 128x128 GEMM (for N=1024: proj / FF2) -------------------
// EPI: 1=+resid->H(f32)  3=+bias+resid->H(f32)
template<int EPI>
__global__ __launch_bounds__(256, 2)
void gemm_k(const u16* __restrict__ A, const u16* __restrict__ Bt,
            int nbn, int K,
            const float* __restrict__ bias, float* __restrict__ H)
{
  __shared__ u16 sm[2][2][128 * 64];   // 64 KB, double buffered A/B tiles
  int cpx = gridDim.x >> 3;
  int logical = (blockIdx.x & 7) * cpx + (blockIdx.x >> 3);
  int bm = logical / nbn, bn = logical % nbn;
  int t = threadIdx.x, lane = t & 63, w = t >> 6;
  int wm = w >> 1, wn = w & 1;
  const u16* Ab = A  + (size_t)(bm * 128) * K;
  const u16* Bb = Bt + (size_t)(bn * 128) * K;
  int nkt = K >> 6;

  stage16k<128>(Ab, K, &sm[0][0][0]);
  stage16k<128>(Bb, K, &sm[0][1][0]);
  __syncthreads();

  const f32x4 vzero = {0.f, 0.f, 0.f, 0.f};
  f32x4 acc[4][4];
#pragma unroll
  for (int i = 0; i < 4; ++i)
#pragma unroll
    for (int j = 0; j < 4; ++j) acc[i][j] = vzero;

  int r0 = lane & 15;
  int kk0 = (lane >> 4) * 8;

  for (int kt = 0; kt < nkt; ++kt) {
    int cur = kt & 1;
    if (kt + 1 < nkt) {
      stage16k<128>(Ab + (kt + 1) * 64, K, &sm[cur ^ 1][0][0]);
      stage16k<128>(Bb + (kt + 1) * 64, K, &sm[cur ^ 1][1][0]);
    }
    const char* smAp = (const char*)&sm[cur][0][0];
    const char* smBp = (const char*)&sm[cur][1][0];
#pragma unroll
    for (int ks = 0; ks < 2; ++ks) {
      int kk = ks * 32 + kk0;
      bf16x8 a[4], b[4];
#pragma unroll
      for (int mf = 0; mf < 4; ++mf) {
        int row = wm * 64 + mf * 16 + r0;
        a[mf] = *(const bf16x8*)(smAp + row * 128 + ((kk * 2) ^ ((row & 7) << 4)));
      }
#pragma unroll
      for (int nf = 0; nf < 4; ++nf) {
        int row = wn * 64 + nf * 16 + r0;
        b[nf] = *(const bf16x8*)(smBp + row * 128 + ((kk * 2) ^ ((row & 7) << 4)));
      }
#pragma unroll
      for (int mf = 0; mf < 4; ++mf)
#pragma unroll
        for (int nf = 0; nf < 4; ++nf)
          acc[mf][nf] = __builtin_amdgcn_mfma_f32_16x16x32_bf16(a[mf], b[nf], acc[mf][nf], 0, 0, 0);
    }
    __syncthreads();
  }

  int m0 = bm * 128 + wm * 64;
  int n0 = bn * 128 + wn * 64;
  int hi = lane >> 4;
#pragma unroll
  for (int mf = 0; mf < 4; ++mf) {
#pragma unroll
    for (int nf = 0; nf < 4; ++nf) {
      int col  = n0 + nf * 16 + r0;
      int rowb = m0 + mf * 16 + hi * 4;
#pragma unroll
      for (int j = 0; j < 4; ++j) {
        int row = rowb + j;
        float v = acc[mf][nf][j];
        size_t idx = (size_t)row * EMB + col;
        if (EPI == 1) H[idx] = v + H[idx];
        else          H[idx] = v + bias[col] + H[idx];
      }
    }
  }
}

// ---------------- fused attention -----------------------------------------
__global__ __launch_bounds__(256, 3)
void attn_k(const u16* __restrict__ Q, const u16* __restrict__ Kk,
            const u16* __restrict__ Vt, u16* __restrict__ AO)
{
  __shared__ u16 kv[2][8192];      // 32 KB staging (K chunks, then V chunks)
  __shared__ u16 Pt[4][2048];      // 16 KB: per-wave P^T chunk [128k][16q]
  int bid = blockIdx.x;
  int bh = (bid & 7) * 32 + (bid >> 6);      // all 8 q-tiles of a bh -> one XCD
  int qt = (bid >> 3) & 7;
  int t = threadIdx.x, lane = t & 63, w = t >> 6;
  const u16* Kb = Kk + (size_t)bh * (NSEQ * HDIM);
  const u16* Vb = Vt + (size_t)bh * (HDIM * NSEQ);
  int r0 = lane & 15, hi = lane >> 4, kk0 = hi * 8;

  int qrow = qt * 64 + w * 16 + r0;
  const u16* Qp = Q + ((size_t)bh * NSEQ + qrow) * HDIM;
  bf16x8 qf0 = *(const bf16x8*)(Qp + kk0);
  bf16x8 qf1 = *(const bf16x8*)(Qp + 32 + kk0);

  const f32x4 vzero = {0.f, 0.f, 0.f, 0.f};
  f32x4 accS[32];
#pragma unroll
  for (int f = 0; f < 32; ++f) accS[f] = vzero;

  stage16k<128>(Kb, HDIM, &kv[0][0]);
  __syncthreads();
#pragma unroll
  for (int kt = 0; kt < 4; ++kt) {
    if (kt < 3) stage16k<128>(Kb + (size_t)(kt + 1) * 128 * HDIM, HDIM, &kv[(kt + 1) & 1][0]);
    const char* smK = (const char*)&kv[kt & 1][0];
#pragma unroll
    for (int nfl = 0; nfl < 8; ++nfl) {
      int krow = nfl * 16 + r0;
      int swz = (krow & 7) << 4;
      bf16x8 b0 = *(const bf16x8*)(smK + krow * 128 + (((kk0)      * 2) ^ swz));
      bf16x8 b1 = *(const bf16x8*)(smK + krow * 128 + (((32 + kk0) * 2) ^ swz));
      accS[kt * 8 + nfl] = __builtin_amdgcn_mfma_f32_16x16x32_bf16(qf0, b0, accS[kt * 8 + nfl], 0, 0, 0);
      accS[kt * 8 + nfl] = __builtin_amdgcn_mfma_f32_16x16x32_bf16(qf1, b1, accS[kt * 8 + nfl], 0, 0, 0);
    }
    __syncthreads();
  }

  stage16k<256>(Vb, NSEQ, &kv[0][0]);

  float mx[4], den[4], rden[4];
#pragma unroll
  for (int j = 0; j < 4; ++j) {
    float m = -1e30f;
#pragma unroll
    for (int f = 0; f < 32; ++f) m = fmaxf(m, accS[f][j]);
    m = fmaxf(m, __shfl_xor(m, 1));
    m = fmaxf(m, __shfl_xor(m, 2));
    m = fmaxf(m, __shfl_xor(m, 4));
    m = fmaxf(m, __shfl_xor(m, 8));
    mx[j] = m;
    den[j] = 0.f;
  }
  uint32_t pb[64];
#pragma unroll
  for (int f = 0; f < 32; ++f) {
    float p0 = __expf((accS[f][0] - mx[0]) * 0.03125f);
    float p1 = __expf((accS[f][1] - mx[1]) * 0.03125f);
    float p2 = __expf((accS[f][2] - mx[2]) * 0.03125f);
    float p3 = __expf((accS[f][3] - mx[3]) * 0.03125f);
    den[0] += p0; den[1] += p1; den[2] += p2; den[3] += p3;
    pb[f * 2 + 0] = (uint32_t)f2bf(p0) | ((uint32_t)f2bf(p1) << 16);
    pb[f * 2 + 1] = (uint32_t)f2bf(p2) | ((uint32_t)f2bf(p3) << 16);
  }
#pragma unroll
  for (int j = 0; j < 4; ++j) {
    float d = den[j];
    d += __shfl_xor(d, 1); d += __shfl_xor(d, 2);
    d += __shfl_xor(d, 4); d += __shfl_xor(d, 8);
    rden[j] = 1.0f / d;
  }
  __syncthreads();

  int perm0 = ((r0 & 4) << 2) + ((r0 >> 3) << 2) + (r0 & 3);
  uint32_t ptb = (uint32_t)(uintptr_t)(as3_u16p)&Pt[w][0];
  uint32_t trBase = ptb + r0 * 2 + hi * 128;
  char* PtW = (char*)&Pt[w][0];

  f32x4 accO[4];
#pragma unroll
  for (int nf = 0; nf < 4; ++nf) accO[nf] = vzero;

#pragma unroll
  for (int kt = 0; kt < 4; ++kt) {
    if (kt < 3) stage16k<256>(Vb + (kt + 1) * 128, NSEQ, &kv[(kt + 1) & 1][0]);
#pragma unroll
    for (int fl = 0; fl < 8; ++fl) {
      int f = kt * 8 + fl;
      int row = (fl >> 1) * 32 + perm0 + ((fl & 1) << 3);
      *(uint2*)(PtW + row * 32 + hi * 8) = make_uint2(pb[f * 2], pb[f * 2 + 1]);
    }
    asm volatile("s_waitcnt lgkmcnt(0)" ::: "memory");
    const char* smV = (const char*)&kv[kt & 1][0];
#pragma unroll
    for (int s = 0; s < 4; ++s) {
      uint2 t0, t1;
      uint32_t a0 = trBase + s * 1024;
      asm volatile("ds_read_b64_tr_b16 %0, %1" : "=v"(t0) : "v"(a0) : "memory");
      asm volatile("ds_read_b64_tr_b16 %0, %1" : "=v"(t1) : "v"(a0 + 512) : "memory");
      bf16x8 vb[4];
#pragma unroll
      for (int nf = 0; nf < 4; ++nf) {
        int d = nf * 16 + r0;
        int inrow = s * 64 + hi * 16;
        vb[nf] = *(const bf16x8*)(smV + d * 256 + (inrow ^ ((d & 7) << 4)));
      }
      asm volatile("s_waitcnt lgkmcnt(0)" ::: "memory");
      __builtin_amdgcn_sched_barrier(0);
      union { uint4 u; bf16x8 v; } pa;
      pa.u = make_uint4(t0.x, t0.y, t1.x, t1.y);
#pragma unroll
      for (int nf = 0; nf < 4; ++nf)
        accO[nf] = __builtin_amdgcn_mfma_f32_16x16x32_bf16(pa.v, vb[nf], accO[nf], 0, 0, 0);
    }
    __syncthreads();
  }

  int b_ = bh >> 4, hh = bh & 15;
#pragma unroll
  for (int nf = 0; nf < 4; ++nf)
#pragma unroll
    for (int j = 0; j < 4; ++j) {
      int ql = hi * 4 + j;
      int tok = qt * 64 + w * 16 + ql;
      int col = hh * 64 + nf * 16 + r0;
      AO[((size_t)(b_ * NSEQ + tok)) * EMB + col] = f2bf(accO[nf][j] * rden[j]);
    }
}

// ---------------- launch ---------------------------------------------------
extern "C" void kernel_launch(void* const* d_in, const int* in_sizes, int n_in,
                              void* d_out, int out_size, void* d_ws, size_t ws_size,
                              hipStream_t stream)
{
  const float* x    = (const float*)d_in[0];
  const float* cls  = (const float*)d_in[1];
  const float* pos  = (const float*)d_in[2];
  const float* Wq   = (const float*)d_in[3];
  const float* Wk   = (const float*)d_in[4];
  const float* Wv   = (const float*)d_in[5];
  const float* Wp   = (const float*)d_in[6];
  const float* ln1g = (const float*)d_in[7];
  const float* ln1b = (const float*)d_in[8];
  const float* ln2g = (const float*)d_in[9];
  const float* ln2b = (const float*)d_in[10];
  const float* W1   = (const float*)d_in[11];
  const float* b1   = (const float*)d_in[12];
  const float* W2   = (const float*)d_in[13];
  const float* b2   = (const float*)d_in[14];
  float* H = (float*)d_out;          // residual stream lives in d_out (fp32)

  char* ws = (char*)d_ws;            // 160 MiB used
  u16* wqkv = (u16*)(ws + 0);                // [6][3072][1024] bf16 (B^T)
  u16* wp   = (u16*)(ws + 37748736);         // [6][1024][1024]
  u16* w1t  = (u16*)(ws + 50331648);         // [6][2048][1024]
  u16* w2t  = (u16*)(ws + 75497472);         // [6][1024][2048]
  u16* xn   = (u16*)(ws + 100663296);        // [8192][1024] (also attn out)
  u16* qb   = (u16*)(ws + 117440512);        // [256][512][64]
  u16* kb   = (u16*)(ws + 134217728);        // [256][512][64]
  u16* vtb  = (u16*)(ws + 150994944);        // [256][64][512]
  u16* ffb  = qb;                            // [8192][2048] aliases q+k

  wprep_k<<<1536, 256, 0, stream>>>(Wq, wqkv, 1024, 1024, 1048576, 3145728, 0);
  wprep_k<<<1536, 256, 0, stream>>>(Wk, wqkv, 1024, 1024, 1048576, 3145728, 1048576);
  wprep_k<<<1536, 256, 0, stream>>>(Wv, wqkv, 1024, 1024, 1048576, 3145728, 2097152);
  wprep_k<<<1536, 256, 0, stream>>>(Wp, wp,   1024, 1024, 1048576, 1048576, 0);
  wprep_k<<<3072, 256, 0, stream>>>(W1, w1t,  1024, 2048, 2097152, 2097152, 0);
  wprep_k<<<3072, 256, 0, stream>>>(W2, w2t,  2048, 1024, 2097152, 2097152, 0);

  embed_k<<<NTOK, 256, 0, stream>>>(x, cls, pos, H);

  for (int l = 0; l < DEPTH; ++l) {
    ln_k<<<NTOK, 256, 0, stream>>>(H, ln1g + l * EMB, ln1b + l * EMB, xn);
    gemm256_k<0><<<384, 512, 0, stream>>>(xn, wqkv + (size_t)l * 3145728, 12, 1024,
                                          nullptr, nullptr, qb, kb, vtb);
    attn_k<<<2048, 256, 0, stream>>>(qb, kb, vtb, xn);
    gemm_k<1><<<512, 256, 0, stream>>>(xn, wp + (size_t)l * 1048576, 8, 1024,
                                       nullptr, H);
    ln_k<<<NTOK, 256, 0, stream>>>(H, ln2g + l * EMB, ln2b + l * EMB, xn);
    gemm256_k<2><<<256, 512, 0, stream>>>(xn, w1t + (size_t)l * 2097152, 8, 1024,
                                          b1 + l * FFD, ffb, nullptr, nullptr, nullptr);
    gemm_k<3><<<512, 256, 0, stream>>>(ffb, w2t + (size_t)l * 2097152, 8, 2048,
                                       b2 + l * EMB, H);
  }
}

// Round 5
// 1530.905 us; speedup vs baseline: 1.0537x; 1.0263x over previous
//
#include <hip/hip_runtime.h>
#include <cstdint>
#include <cstddef>

#define DEPTH 6
#define NB    16
#define NSEQ  512
#define EMB   1024
#define NHEAD 16
#define HDIM  64
#define FFD   2048
#define NTOK  (NB * NSEQ)   // 8192

typedef unsigned short u16;
using bf16x8 = __attribute__((ext_vector_type(8))) __bf16;
using f32x4  = __attribute__((ext_vector_type(4))) float;
using u16x4  = __attribute__((ext_vector_type(4))) u16;
using u16x8  = __attribute__((ext_vector_type(8))) u16;

typedef __attribute__((address_space(1))) uint32_t* as1_u32p;
typedef __attribute__((address_space(3))) uint32_t* as3_u32p;
typedef __attribute__((address_space(3))) u16*      as3_u16p;

__device__ __forceinline__ u16 f2bf(float f) {
  union { float f; uint32_t u; } v; v.f = f;
  uint32_t u = v.u;
  return (u16)((u + 0x7FFFu + ((u >> 16) & 1u)) >> 16);
}

__device__ __forceinline__ void gload_lds16(const u16* g, u16* l) {
  void* gp = const_cast<u16*>(g);
  __builtin_amdgcn_global_load_lds((as1_u32p)gp, (as3_u32p)l, 16, 0, 0);
}

// Stage a 16KB tile (rows of ROWBYTES bytes) global->LDS, linear LDS dest,
// XOR-swizzled global source so that reads with byte^((row&7)<<4) are
// bank-conflict-free (rule #21). 256-thread version.
template<int ROWBYTES>
__device__ __forceinline__ void stage16k(const u16* g0, int ldk, u16* lds) {
  int t = threadIdx.x;
#pragma unroll
  for (int i = 0; i < 4; ++i) {
    int off = (i * 256 + t) * 16;          // LDS byte offset
    int row = off / ROWBYTES;
    int pc  = (off % ROWBYTES) >> 4;
    int lc  = pc ^ (row & 7);
    gload_lds16(g0 + (size_t)row * ldk + lc * 8, lds + (off >> 1));
  }
}

// ---------------- weight prep: fp32 [K][N] -> bf16 [N][K] (B^T layout) ----
__global__ __launch_bounds__(256)
void wprep_k(const float* __restrict__ W, u16* __restrict__ Wt,
             int K, int N, size_t inL, size_t outL, size_t outOff)
{
  int ntiles = N >> 6, ktiles = K >> 6;
  int bid = blockIdx.x;
  int l = bid / (ktiles * ntiles);
  int r = bid % (ktiles * ntiles);
  int kt = r / ntiles, nt = r % ntiles;
  const float* in = W + (size_t)l * inL + (size_t)(kt * 64) * N + nt * 64;
  u16* out = Wt + (size_t)l * outL + outOff + (size_t)(nt * 64) * K + kt * 64;
  __shared__ float tile[64][65];
  int t = threadIdx.x;
  int tr = t >> 4, tc = (t & 15) * 4;
#pragma unroll
  for (int i = 0; i < 4; ++i) {
    f32x4 v = *(const f32x4*)(in + (size_t)(tr + i * 16) * N + tc);
    tile[tr + i * 16][tc + 0] = v[0];
    tile[tr + i * 16][tc + 1] = v[1];
    tile[tr + i * 16][tc + 2] = v[2];
    tile[tr + i * 16][tc + 3] = v[3];
  }
  __syncthreads();
#pragma unroll
  for (int i = 0; i < 4; ++i) {
    int nr = tr + i * 16;
    u16x4 o;
    o[0] = f2bf(tile[tc + 0][nr]);
    o[1] = f2bf(tile[tc + 1][nr]);
    o[2] = f2bf(tile[tc + 2][nr]);
    o[3] = f2bf(tile[tc + 3][nr]);
    *(u16x4*)(out + (size_t)nr * K + tc) = o;
  }
}

// ---------------- embed: concat cls + pos add ------------------------------
__global__ __launch_bounds__(256)
void embed_k(const float* __restrict__ x, const float* __restrict__ cls,
             const float* __restrict__ pos, float* __restrict__ H)
{
  int row = blockIdx.x, t = threadIdx.x;
  int b_ = row >> 9, n = row & 511;
  int c = t * 4;
  f32x4 p = *(const f32x4*)(pos + (size_t)n * EMB + c);
  f32x4 s;
  if (n == 0) s = *(const f32x4*)(cls + c);
  else        s = *(const f32x4*)(x + ((size_t)b_ * 511 + (n - 1)) * EMB + c);
  f32x4 o = s + p;
  *(f32x4*)(H + (size_t)row * EMB + c) = o;
}

// ---------------- layernorm: fp32 h -> bf16 xn ----------------------------
__global__ __launch_bounds__(256)
void ln_k(const float* __restrict__ H, const float* __restrict__ g,
          const float* __restrict__ b, u16* __restrict__ out)
{
  int row = blockIdx.x, t = threadIdx.x;
  const float* hp = H + (size_t)row * EMB;
  f32x4 v = *(const f32x4*)(hp + t * 4);
  float s  = v[0] + v[1] + v[2] + v[3];
  float ss = v[0]*v[0] + v[1]*v[1] + v[2]*v[2] + v[3]*v[3];
#pragma unroll
  for (int m = 1; m <= 32; m <<= 1) { s += __shfl_xor(s, m); ss += __shfl_xor(ss, m); }
  __shared__ float red[8];
  if ((t & 63) == 0) { red[(t >> 6) * 2] = s; red[(t >> 6) * 2 + 1] = ss; }
  __syncthreads();
  float S  = red[0] + red[2] + red[4] + red[6];
  float SS = red[1] + red[3] + red[5] + red[7];
  float mean = S * (1.0f / EMB);
  float var  = SS * (1.0f / EMB) - mean * mean;
  float rs = rsqrtf(var + 1e-5f);
  f32x4 gg = *(const f32x4*)(g + t * 4);
  f32x4 bb = *(const f32x4*)(b + t * 4);
  u16x4 o;
#pragma unroll
  for (int i = 0; i < 4; ++i) o[i] = f2bf((v[i] - mean) * rs * gg[i] + bb[i]);
  *(u16x4*)(out + (size_t)row * EMB + t * 4) = o;
}

// ================= 128x128 GEMM, m97-exact single-buffer (32KB LDS) =======
// C[8192][N] = A[8192][K] * Bt[N][K]^T.  4 waves (2x2), BK=64, 3 blocks/CU.
// EPI: 0=QKV scatter via LDS-coalesced epi  1=+resid->H(f32)
//      2=+bias,gelu->outB via LDS epi       3=+bias+resid->H(f32)
// Epilogue LDS swizzle: elem(row,col) at row*128 + (col&7) + (((col>>3)^(row&7))<<3)
template<int EPI>
__global__ __launch_bounds__(256, 3)
void gemm_k(const u16* __restrict__ A, const u16* __restrict__ Bt,
            int nbn, int K,
            const float* __restrict__ bias, float* __restrict__ H,
            u16* __restrict__ outB,
            u16* __restrict__ qo, u16* __restrict__ ko, u16* __restrict__ vto)
{
  __shared__ u16 sm[16384];            // 32 KB: A tile | B tile; reused by epi
  int cpx = gridDim.x >> 3;
  int logical = (blockIdx.x & 7) * cpx + (blockIdx.x >> 3);
  int bm = logical / nbn, bn = logical % nbn;
  int t = threadIdx.x, lane = t & 63, w = t >> 6;
  int wm = w >> 1, wn = w & 1;
  const u16* Ab = A  + (size_t)(bm * 128) * K;
  const u16* Bb = Bt + (size_t)(bn * 128) * K;
  int nkt = K >> 6;

  const f32x4 vzero = {0.f, 0.f, 0.f, 0.f};
  f32x4 acc[4][4];
#pragma unroll
  for (int i = 0; i < 4; ++i)
#pragma unroll
    for (int j = 0; j < 4; ++j) acc[i][j] = vzero;

  int r0 = lane & 15;
  int hi = lane >> 4;
  int kk0 = hi * 8;

  for (int kt = 0; kt < nkt; ++kt) {
    stage16k<128>(Ab + kt * 64, K, sm);
    stage16k<128>(Bb + kt * 64, K, sm + 8192);
    __syncthreads();                    // drains vmcnt: tile ready
    const char* smAp = (const char*)sm;
    const char* smBp = (const char*)(sm + 8192);
#pragma unroll
    for (int ks = 0; ks < 2; ++ks) {
      int kk = ks * 32 + kk0;
      bf16x8 a[4], b[4];
#pragma unroll
      for (int mf = 0; mf < 4; ++mf) {
        int row = wm * 64 + mf * 16 + r0;
        a[mf] = *(const bf16x8*)(smAp + row * 128 + ((kk * 2) ^ ((row & 7) << 4)));
      }
#pragma unroll
      for (int nf = 0; nf < 4; ++nf) {
        int row = wn * 64 + nf * 16 + r0;
        b[nf] = *(const bf16x8*)(smBp + row * 128 + ((kk * 2) ^ ((row & 7) << 4)));
      }
#pragma unroll
      for (int mf = 0; mf < 4; ++mf)
#pragma unroll
        for (int nf = 0; nf < 4; ++nf)
          acc[mf][nf] = __builtin_amdgcn_mfma_f32_16x16x32_bf16(a[mf], b[nf], acc[mf][nf], 0, 0, 0);
    }
    __syncthreads();                    // readers done; next stage may overwrite
  }

  if (EPI == 1 || EPI == 3) {
    int m0 = bm * 128 + wm * 64;
    int n0 = bn * 128 + wn * 64;
#pragma unroll
    for (int mf = 0; mf < 4; ++mf) {
#pragma unroll
      for (int nf = 0; nf < 4; ++nf) {
        int col  = n0 + nf * 16 + r0;
        int rowb = m0 + mf * 16 + hi * 4;
#pragma unroll
        for (int j = 0; j < 4; ++j) {
          float v = acc[mf][nf][j];
          size_t idx = (size_t)(rowb + j) * EMB + col;
          if (EPI == 1) H[idx] = v + H[idx];
          else          H[idx] = v + bias[col] + H[idx];
        }
      }
    }
    return;
  }

  // ---- LDS-coalesced epilogue (EPI 0 / 2) --------------------------------
  int sec = (bn * 128) >> 10;           // EPI0: 0=q 1=k 2=v ; EPI2: always 0/1
  bool vsec = (EPI == 0) && (sec == 2);
#pragma unroll
  for (int mf = 0; mf < 4; ++mf) {
#pragma unroll
    for (int nf = 0; nf < 4; ++nf) {
      int colL = wn * 64 + nf * 16 + r0;
#pragma unroll
      for (int j = 0; j < 4; ++j) {
        int rowL = wm * 64 + mf * 16 + hi * 4 + j;
        float v = acc[mf][nf][j];
        if (EPI == 2) {
          float xg = v + bias[bn * 128 + colL];
          v = 0.5f * xg * (1.0f + erff(xg * 0.70710678118654752f));
        }
        u16 o = f2bf(v);
        if (!vsec)
          sm[rowL * 128 + (colL & 7) + ((((colL >> 3) ^ (rowL & 7))) << 3)] = o;
        else  // v: store transposed [c][n]
          sm[colL * 128 + (rowL & 7) + ((((rowL >> 3) ^ (colL & 7))) << 3)] = o;
      }
    }
  }
  __syncthreads();

  int c  = t & 15;                      // chunk of 8 cols
  int rb = t >> 4;
  if (!vsec) {
#pragma unroll
    for (int i = 0; i < 8; ++i) {
      int row = rb * 8 + i;
      u16x8 v = *(const u16x8*)(sm + row * 128 + ((c ^ (row & 7)) << 3));
      if (EPI == 2) {
        int rowg = bm * 128 + row;
        int colg = bn * 128 + c * 8;
        *(u16x8*)(outB + (size_t)rowg * FFD + colg) = v;
      } else {
        int n_ = bm * 128 + row;
        int b_ = n_ >> 9, tok = n_ & 511;
        int c0 = (bn * 128 - sec * 1024) + c * 8;
        int hh = c0 >> 6, d0 = c0 & 63;
        u16* dst = (sec == 0) ? qo : ko;
        *(u16x8*)(dst + (((size_t)(b_ * NHEAD + hh) * NSEQ + tok) * HDIM) + d0) = v;
      }
    }
  } else {
#pragma unroll
    for (int i = 0; i < 8; ++i) {
      int rowp = rb * 8 + i;            // local c (head*64+d)
      u16x8 v = *(const u16x8*)(sm + rowp * 128 + ((c ^ (rowp & 7)) << 3));
      int c0 = (bn * 128 - 2048) + rowp;
      int hh = c0 >> 6, d = c0 & 63;
      int tok0 = bm * 128 + c * 8;
      int b_ = tok0 >> 9;
      *(u16x8*)(vto + ((size_t)(b_ * NHEAD + hh) * HDIM + d) * NSEQ + (tok0 & 511)) = v;
    }
  }
}

// ---------------- fused attention -----------------------------------------
__global__ __launch_bounds__(256, 3)
void attn_k(const u16* __restrict__ Q, const u16* __restrict__ Kk,
            const u16* __restrict__ Vt, u16* __restrict__ AO)
{
  __shared__ u16 kv[2][8192];      // 32 KB staging (K chunks, then V chunks)
  __shared__ u16 Pt[4][2048];      // 16 KB: per-wave P^T chunk [128k][16q]
  int bid = blockIdx.x;
  int bh = (bid & 7) * 32 + (bid >> 6);      // all 8 q-tiles of a bh -> one XCD
  int qt = (bid >> 3) & 7;
  int t = threadIdx.x, lane = t & 63, w = t >> 6;
  const u16* Kb = Kk + (size_t)bh * (NSEQ * HDIM);
  const u16* Vb = Vt + (size_t)bh * (HDIM * NSEQ);
  int r0 = lane & 15, hi = lane >> 4, kk0 = hi * 8;

  int qrow = qt * 64 + w * 16 + r0;
  const u16* Qp = Q + ((size_t)bh * NSEQ + qrow) * HDIM;
  bf16x8 qf0 = *(const bf16x8*)(Qp + kk0);
  bf16x8 qf1 = *(const bf16x8*)(Qp + 32 + kk0);

  const f32x4 vzero = {0.f, 0.f, 0.f, 0.f};
  f32x4 accS[32];
#pragma unroll
  for (int f = 0; f < 32; ++f) accS[f] = vzero;

  stage16k<128>(Kb, HDIM, &kv[0][0]);
  __syncthreads();
#pragma unroll
  for (int kt = 0; kt < 4; ++kt) {
    if (kt < 3) stage16k<128>(Kb + (size_t)(kt + 1) * 128 * HDIM, HDIM, &kv[(kt + 1) & 1][0]);
    const char* smK = (const char*)&kv[kt & 1][0];
#pragma unroll
    for (int nfl = 0; nfl < 8; ++nfl) {
      int krow = nfl * 16 + r0;
      int swz = (krow & 7) << 4;
      bf16x8 b0 = *(const bf16x8*)(smK + krow * 128 + (((kk0)      * 2) ^ swz));
      bf16x8 b1 = *(const bf16x8*)(smK + krow * 128 + (((32 + kk0) * 2) ^ swz));
      accS[kt * 8 + nfl] = __builtin_amdgcn_mfma_f32_16x16x32_bf16(qf0, b0, accS[kt * 8 + nfl], 0, 0, 0);
      accS[kt * 8 + nfl] = __builtin_amdgcn_mfma_f32_16x16x32_bf16(qf1, b1, accS[kt * 8 + nfl], 0, 0, 0);
    }
    __syncthreads();
  }

  stage16k<256>(Vb, NSEQ, &kv[0][0]);

  float mx[4], den[4], rden[4];
#pragma unroll
  for (int j = 0; j < 4; ++j) {
    float m = -1e30f;
#pragma unroll
    for (int f = 0; f < 32; ++f) m = fmaxf(m, accS[f][j]);
    m = fmaxf(m, __shfl_xor(m, 1));
    m = fmaxf(m, __shfl_xor(m, 2));
    m = fmaxf(m, __shfl_xor(m, 4));
    m = fmaxf(m, __shfl_xor(m, 8));
    mx[j] = m;
    den[j] = 0.f;
  }
  uint32_t pb[64];
#pragma unroll
  for (int f = 0; f < 32; ++f) {
    float p0 = __expf((accS[f][0] - mx[0]) * 0.03125f);
    float p1 = __expf((accS[f][1] - mx[1]) * 0.03125f);
    float p2 = __expf((accS[f][2] - mx[2]) * 0.03125f);
    float p3 = __expf((accS[f][3] - mx[3]) * 0.03125f);
    den[0] += p0; den[1] += p1; den[2] += p2; den[3] += p3;
    pb[f * 2 + 0] = (uint32_t)f2bf(p0) | ((uint32_t)f2bf(p1) << 16);
    pb[f * 2 + 1] = (uint32_t)f2bf(p2) | ((uint32_t)f2bf(p3) << 16);
  }
#pragma unroll
  for (int j = 0; j < 4; ++j) {
    float d = den[j];
    d += __shfl_xor(d, 1); d += __shfl_xor(d, 2);
    d += __shfl_xor(d, 4); d += __shfl_xor(d, 8);
    rden[j] = 1.0f / d;
  }
  __syncthreads();

  int perm0 = ((r0 & 4) << 2) + ((r0 >> 3) << 2) + (r0 & 3);
  uint32_t ptb = (uint32_t)(uintptr_t)(as3_u16p)&Pt[w][0];
  uint32_t trBase = ptb + r0 * 2 + hi * 128;
  char* PtW = (char*)&Pt[w][0];

  f32x4 accO[4];
#pragma unroll
  for (int nf = 0; nf < 4; ++nf) accO[nf] = vzero;

#pragma unroll
  for (int kt = 0; kt < 4; ++kt) {
    if (kt < 3) stage16k<256>(Vb + (kt + 1) * 128, NSEQ, &kv[(kt + 1) & 1][0]);
#pragma unroll
    for (int fl = 0; fl < 8; ++fl) {
      int f = kt * 8 + fl;
      int row = (fl >> 1) * 32 + perm0 + ((fl & 1) << 3);
      *(uint2*)(PtW + row * 32 + hi * 8) = make_uint2(pb[f * 2], pb[f * 2 + 1]);
    }
    asm volatile("s_waitcnt lgkmcnt(0)" ::: "memory");
    const char* smV = (const char*)&kv[kt & 1][0];
#pragma unroll
    for (int s = 0; s < 4; ++s) {
      uint2 t0, t1;
      uint32_t a0 = trBase + s * 1024;
      asm volatile("ds_read_b64_tr_b16 %0, %1" : "=v"(t0) : "v"(a0) : "memory");
      asm volatile("ds_read_b64_tr_b16 %0, %1" : "=v"(t1) : "v"(a0 + 512) : "memory");
      bf16x8 vb[4];
#pragma unroll
      for (int nf = 0; nf < 4; ++nf) {
        int d = nf * 16 + r0;
        int inrow = s * 64 + hi * 16;
        vb[nf] = *(const bf16x8*)(smV + d * 256 + (inrow ^ ((d & 7) << 4)));
      }
      asm volatile("s_waitcnt lgkmcnt(0)" ::: "memory");
      __builtin_amdgcn_sched_barrier(0);
      union { uint4 u; bf16x8 v; } pa;
      pa.u = make_uint4(t0.x, t0.y, t1.x, t1.y);
#pragma unroll
      for (int nf = 0; nf < 4; ++nf)
        accO[nf] = __builtin_amdgcn_mfma_f32_16x16x32_bf16(pa.v, vb[nf], accO[nf], 0, 0, 0);
    }
    __syncthreads();
  }

  int b_ = bh >> 4, hh = bh & 15;
#pragma unroll
  for (int nf = 0; nf < 4; ++nf)
#pragma unroll
    for (int j = 0; j < 4; ++j) {
      int ql = hi * 4 + j;
      int tok = qt * 64 + w * 16 + ql;
      int col = hh * 64 + nf * 16 + r0;
      AO[((size_t)(b_ * NSEQ + tok)) * EMB + col] = f2bf(accO[nf][j] * rden[j]);
    }
}

// ---------------- launch ---------------------------------------------------
extern "C" void kernel_launch(void* const* d_in, const int* in_sizes, int n_in,
                              void* d_out, int out_size, void* d_ws, size_t ws_size,
                              hipStream_t stream)
{
  const float* x    = (const float*)d_in[0];
  const float* cls  = (const float*)d_in[1];
  const float* pos  = (const float*)d_in[2];
  const float* Wq   = (const float*)d_in[3];
  const float* Wk   = (const float*)d_in[4];
  const float* Wv   = (const float*)d_in[5];
  const float* Wp   = (const float*)d_in[6];
  const float* ln1g = (const float*)d_in[7];
  const float* ln1b = (const float*)d_in[8];
  const float* ln2g = (const float*)d_in[9];
  const float* ln2b = (const float*)d_in[10];
  const float* W1   = (const float*)d_in[11];
  const float* b1   = (const float*)d_in[12];
  const float* W2   = (const float*)d_in[13];
  const float* b2   = (const float*)d_in[14];
  float* H = (float*)d_out;          // residual stream lives in d_out (fp32)

  char* ws = (char*)d_ws;            // 160 MiB used
  u16* wqkv = (u16*)(ws + 0);                // [6][3072][1024] bf16 (B^T)
  u16* wp   = (u16*)(ws + 37748736);         // [6][1024][1024]
  u16* w1t  = (u16*)(ws + 50331648);         // [6][2048][1024]
  u16* w2t  = (u16*)(ws + 75497472);         // [6][1024][2048]
  u16* xn   = (u16*)(ws + 100663296);        // [8192][1024] (also attn out)
  u16* qb   = (u16*)(ws + 117440512);        // [256][512][64]
  u16* kb   = (u16*)(ws + 134217728);        // [256][512][64]
  u16* vtb  = (u16*)(ws + 150994944);        // [256][64][512]
  u16* ffb  = qb;                            // [8192][2048] aliases q+k

  wprep_k<<<1536, 256, 0, stream>>>(Wq, wqkv, 1024, 1024, 1048576, 3145728, 0);
  wprep_k<<<1536, 256, 0, stream>>>(Wk, wqkv, 1024, 1024, 1048576, 3145728, 1048576);
  wprep_k<<<1536, 256, 0, stream>>>(Wv, wqkv, 1024, 1024, 1048576, 3145728, 2097152);
  wprep_k<<<1536, 256, 0, stream>>>(Wp, wp,   1024, 1024, 1048576, 1048576, 0);
  wprep_k<<<3072, 256, 0, stream>>>(W1, w1t,  1024, 2048, 2097152, 2097152, 0);
  wprep_k<<<3072, 256, 0, stream>>>(W2, w2t,  2048, 1024, 2097152, 2097152, 0);

  embed_k<<<NTOK, 256, 0, stream>>>(x, cls, pos, H);

  for (int l = 0; l < DEPTH; ++l) {
    ln_k<<<NTOK, 256, 0, stream>>>(H, ln1g + l * EMB, ln1b + l * EMB, xn);
    gemm_k<0><<<64 * 24, 256, 0, stream>>>(xn, wqkv + (size_t)l * 3145728, 24, 1024,
                                           nullptr, nullptr, nullptr, qb, kb, vtb);
    attn_k<<<2048, 256, 0, stream>>>(qb, kb, vtb, xn);
    gemm_k<1><<<64 * 8, 256, 0, stream>>>(xn, wp + (size_t)l * 1048576, 8, 1024,
                                          nullptr, H, nullptr, nullptr, nullptr, nullptr);
    ln_k<<<NTOK, 256, 0, stream>>>(H, ln2g + l * EMB, ln2b + l * EMB, xn);
    gemm_k<2><<<64 * 16, 256, 0, stream>>>(xn, w1t + (size_t)l * 2097152, 16, 1024,
                                           b1 + l * FFD, nullptr, ffb, nullptr, nullptr, nullptr);
    gemm_k<3><<<64 * 8, 256, 0, stream>>>(ffb, w2t + (size_t)l * 2097152, 8, 2048,
                                          b2 + l * EMB, H, nullptr, nullptr, nullptr, nullptr);
  }
}

// Round 6
// 1524.506 us; speedup vs baseline: 1.0581x; 1.0042x over previous
//
#include <hip/hip_runtime.h>
#include <cstdint>
#include <cstddef>

#define DEPTH 6
#define NB    16
#define NSEQ  512
#define EMB   1024
#define NHEAD 16
#define HDIM  64
#define FFD   2048
#define NTOK  (NB * NSEQ)   // 8192

typedef unsigned short u16;
using bf16x8 = __attribute__((ext_vector_type(8))) __bf16;
using f32x4  = __attribute__((ext_vector_type(4))) float;
using u16x4  = __attribute__((ext_vector_type(4))) u16;
using u16x8  = __attribute__((ext_vector_type(8))) u16;

typedef __attribute__((address_space(1))) uint32_t* as1_u32p;
typedef __attribute__((address_space(3))) uint32_t* as3_u32p;
typedef __attribute__((address_space(3))) u16*      as3_u16p;

__device__ __forceinline__ u16 f2bf(float f) {
  union { float f; uint32_t u; } v; v.f = f;
  uint32_t u = v.u;
  return (u16)((u + 0x7FFFu + ((u >> 16) & 1u)) >> 16);
}

__device__ __forceinline__ void gload_lds16(const u16* g, u16* l) {
  void* gp = const_cast<u16*>(g);
  __builtin_amdgcn_global_load_lds((as1_u32p)gp, (as3_u32p)l, 16, 0, 0);
}

// Stage a 16KB tile (rows of ROWBYTES bytes) global->LDS, linear LDS dest,
// XOR-swizzled global source so that reads with byte^((row&7)<<4) are
// bank-conflict-free (rule #21). 256-thread version.
template<int ROWBYTES>
__device__ __forceinline__ void stage16k(const u16* g0, int ldk, u16* lds) {
  int t = threadIdx.x;
#pragma unroll
  for (int i = 0; i < 4; ++i) {
    int off = (i * 256 + t) * 16;          // LDS byte offset
    int row = off / ROWBYTES;
    int pc  = (off % ROWBYTES) >> 4;
    int lc  = pc ^ (row & 7);
    gload_lds16(g0 + (size_t)row * ldk + lc * 8, lds + (off >> 1));
  }
}

// ---------------- weight prep: fp32 [K][N] -> bf16 [N][K] (B^T layout) ----
__global__ __launch_bounds__(256)
void wprep_k(const float* __restrict__ W, u16* __restrict__ Wt,
             int K, int N, size_t inL, size_t outL, size_t outOff)
{
  int ntiles = N >> 6, ktiles = K >> 6;
  int bid = blockIdx.x;
  int l = bid / (ktiles * ntiles);
  int r = bid % (ktiles * ntiles);
  int kt = r / ntiles, nt = r % ntiles;
  const float* in = W + (size_t)l * inL + (size_t)(kt * 64) * N + nt * 64;
  u16* out = Wt + (size_t)l * outL + outOff + (size_t)(nt * 64) * K + kt * 64;
  __shared__ float tile[64][65];
  int t = threadIdx.x;
  int tr = t >> 4, tc = (t & 15) * 4;
#pragma unroll
  for (int i = 0; i < 4; ++i) {
    f32x4 v = *(const f32x4*)(in + (size_t)(tr + i * 16) * N + tc);
    tile[tr + i * 16][tc + 0] = v[0];
    tile[tr + i * 16][tc + 1] = v[1];
    tile[tr + i * 16][tc + 2] = v[2];
    tile[tr + i * 16][tc + 3] = v[3];
  }
  __syncthreads();
#pragma unroll
  for (int i = 0; i < 4; ++i) {
    int nr = tr + i * 16;
    u16x4 o;
    o[0] = f2bf(tile[tc + 0][nr]);
    o[1] = f2bf(tile[tc + 1][nr]);
    o[2] = f2bf(tile[tc + 2][nr]);
    o[3] = f2bf(tile[tc + 3][nr]);
    *(u16x4*)(out + (size_t)nr * K + tc) = o;
  }
}

// ---------------- embed: concat cls + pos add ------------------------------
__global__ __launch_bounds__(256)
void embed_k(const float* __restrict__ x, const float* __restrict__ cls,
             const float* __restrict__ pos, float* __restrict__ H)
{
  int row = blockIdx.x, t = threadIdx.x;
  int b_ = row >> 9, n = row & 511;
  int c = t * 4;
  f32x4 p = *(const f32x4*)(pos + (size_t)n * EMB + c);
  f32x4 s;
  if (n == 0) s = *(const f32x4*)(cls + c);
  else        s = *(const f32x4*)(x + ((size_t)b_ * 511 + (n - 1)) * EMB + c);
  f32x4 o = s + p;
  *(f32x4*)(H + (size_t)row * EMB + c) = o;
}

// ---------------- layernorm: fp32 h -> bf16 xn ----------------------------
__global__ __launch_bounds__(256)
void ln_k(const float* __restrict__ H, const float* __restrict__ g,
          const float* __restrict__ b, u16* __restrict__ out)
{
  int row = blockIdx.x, t = threadIdx.x;
  const float* hp = H + (size_t)row * EMB;
  f32x4 v = *(const f32x4*)(hp + t * 4);
  float s  = v[0] + v[1] + v[2] + v[3];
  float ss = v[0]*v[0] + v[1]*v[1] + v[2]*v[2] + v[3]*v[3];
#pragma unroll
  for (int m = 1; m <= 32; m <<= 1) { s += __shfl_xor(s, m); ss += __shfl_xor(ss, m); }
  __shared__ float red[8];
  if ((t & 63) == 0) { red[(t >> 6) * 2] = s; red[(t >> 6) * 2 + 1] = ss; }
  __syncthreads();
  float S  = red[0] + red[2] + red[4] + red[6];
  float SS = red[1] + red[3] + red[5] + red[7];
  float mean = S * (1.0f / EMB);
  float var  = SS * (1.0f / EMB) - mean * mean;
  float rs = rsqrtf(var + 1e-5f);
  f32x4 gg = *(const f32x4*)(g + t * 4);
  f32x4 bb = *(const f32x4*)(b + t * 4);
  u16x4 o;
#pragma unroll
  for (int i = 0; i < 4; ++i) o[i] = f2bf((v[i] - mean) * rs * gg[i] + bb[i]);
  *(u16x4*)(out + (size_t)row * EMB + t * 4) = o;
}

// ================= 128x128 GEMM, m97-exact single-buffer (32KB LDS) =======
// C[8192][N] = A[8192][K] * Bt[N][K]^T.  4 waves (2x2), BK=64, 3 blocks/CU.
// EPI: 0=QKV scatter via LDS-coalesced epi  1=+resid->H(f32)
//      2=+bias,gelu->outB via LDS epi       3=+bias+resid->H(f32)
template<int EPI>
__global__ __launch_bounds__(256, 3)
void gemm_k(const u16* __restrict__ A, const u16* __restrict__ Bt,
            int nbn, int K,
            const float* __restrict__ bias, float* __restrict__ H,
            u16* __restrict__ outB,
            u16* __restrict__ qo, u16* __restrict__ ko, u16* __restrict__ vto)
{
  __shared__ u16 sm[16384];            // 32 KB: A tile | B tile; reused by epi
  int cpx = gridDim.x >> 3;
  int logical = (blockIdx.x & 7) * cpx + (blockIdx.x >> 3);
  int bm = logical / nbn, bn = logical % nbn;
  int t = threadIdx.x, lane = t & 63, w = t >> 6;
  int wm = w >> 1, wn = w & 1;
  const u16* Ab = A  + (size_t)(bm * 128) * K;
  const u16* Bb = Bt + (size_t)(bn * 128) * K;
  int nkt = K >> 6;

  const f32x4 vzero = {0.f, 0.f, 0.f, 0.f};
  f32x4 acc[4][4];
#pragma unroll
  for (int i = 0; i < 4; ++i)
#pragma unroll
    for (int j = 0; j < 4; ++j) acc[i][j] = vzero;

  int r0 = lane & 15;
  int hi = lane >> 4;
  int kk0 = hi * 8;

  for (int kt = 0; kt < nkt; ++kt) {
    stage16k<128>(Ab + kt * 64, K, sm);
    stage16k<128>(Bb + kt * 64, K, sm + 8192);
    __syncthreads();                    // drains vmcnt: tile ready
    const char* smAp = (const char*)sm;
    const char* smBp = (const char*)(sm + 8192);
#pragma unroll
    for (int ks = 0; ks < 2; ++ks) {
      int kk = ks * 32 + kk0;
      bf16x8 a[4], b[4];
#pragma unroll
      for (int mf = 0; mf < 4; ++mf) {
        int row = wm * 64 + mf * 16 + r0;
        a[mf] = *(const bf16x8*)(smAp + row * 128 + ((kk * 2) ^ ((row & 7) << 4)));
      }
#pragma unroll
      for (int nf = 0; nf < 4; ++nf) {
        int row = wn * 64 + nf * 16 + r0;
        b[nf] = *(const bf16x8*)(smBp + row * 128 + ((kk * 2) ^ ((row & 7) << 4)));
      }
#pragma unroll
      for (int mf = 0; mf < 4; ++mf)
#pragma unroll
        for (int nf = 0; nf < 4; ++nf)
          acc[mf][nf] = __builtin_amdgcn_mfma_f32_16x16x32_bf16(a[mf], b[nf], acc[mf][nf], 0, 0, 0);
    }
    __syncthreads();                    // readers done; next stage may overwrite
  }

  if (EPI == 1 || EPI == 3) {
    int m0 = bm * 128 + wm * 64;
    int n0 = bn * 128 + wn * 64;
#pragma unroll
    for (int mf = 0; mf < 4; ++mf) {
#pragma unroll
      for (int nf = 0; nf < 4; ++nf) {
        int col  = n0 + nf * 16 + r0;
        int rowb = m0 + mf * 16 + hi * 4;
#pragma unroll
        for (int j = 0; j < 4; ++j) {
          float v = acc[mf][nf][j];
          size_t idx = (size_t)(rowb + j) * EMB + col;
          if (EPI == 1) H[idx] = v + H[idx];
          else          H[idx] = v + bias[col] + H[idx];
        }
      }
    }
    return;
  }

  // ---- LDS-coalesced epilogue (EPI 0 / 2) --------------------------------
  int sec = (bn * 128) >> 10;           // EPI0: 0=q 1=k 2=v ; EPI2: always 0/1
  bool vsec = (EPI == 0) && (sec == 2);
#pragma unroll
  for (int mf = 0; mf < 4; ++mf) {
#pragma unroll
    for (int nf = 0; nf < 4; ++nf) {
      int colL = wn * 64 + nf * 16 + r0;
#pragma unroll
      for (int j = 0; j < 4; ++j) {
        int rowL = wm * 64 + mf * 16 + hi * 4 + j;
        float v = acc[mf][nf][j];
        if (EPI == 2) {
          float xg = v + bias[bn * 128 + colL];
          v = 0.5f * xg * (1.0f + erff(xg * 0.70710678118654752f));
        }
        u16 o = f2bf(v);
        if (!vsec)
          sm[rowL * 128 + (colL & 7) + ((((colL >> 3) ^ (rowL & 7))) << 3)] = o;
        else  // v: store transposed [c][n]
          sm[colL * 128 + (rowL & 7) + ((((rowL >> 3) ^ (colL & 7))) << 3)] = o;
      }
    }
  }
  __syncthreads();

  int c  = t & 15;                      // chunk of 8 cols
  int rb = t >> 4;
  if (!vsec) {
#pragma unroll
    for (int i = 0; i < 8; ++i) {
      int row = rb * 8 + i;
      u16x8 v = *(const u16x8*)(sm + row * 128 + ((c ^ (row & 7)) << 3));
      if (EPI == 2) {
        int rowg = bm * 128 + row;
        int colg = bn * 128 + c * 8;
        *(u16x8*)(outB + (size_t)rowg * FFD + colg) = v;
      } else {
        int n_ = bm * 128 + row;
        int b_ = n_ >> 9, tok = n_ & 511;
        int c0 = (bn * 128 - sec * 1024) + c * 8;
        int hh = c0 >> 6, d0 = c0 & 63;
        u16* dst = (sec == 0) ? qo : ko;
        *(u16x8*)(dst + (((size_t)(b_ * NHEAD + hh) * NSEQ + tok) * HDIM) + d0) = v;
      }
    }
  } else {
#pragma unroll
    for (int i = 0; i < 8; ++i) {
      int rowp = rb * 8 + i;            // local c (head*64+d)
      u16x8 v = *(const u16x8*)(sm + rowp * 128 + ((c ^ (rowp & 7)) << 3));
      int c0 = (bn * 128 - 2048) + rowp;
      int hh = c0 >> 6, d = c0 & 63;
      int tok0 = bm * 128 + c * 8;
      int b_ = tok0 >> 9;
      *(u16x8*)(vto + ((size_t)(b_ * NHEAD + hh) * HDIM + d) * NSEQ + (tok0 & 511)) = v;
    }
  }
}

// ---------------- fused attention: 3-barrier schedule ----------------------
// Stage ALL of K (64KB) -> bar -> S-phase barrier-free -> bar -> stage V^T
// into same region with softmax under the loads -> bar -> PV wave-private.
__global__ __launch_bounds__(256, 2)
void attn_k(const u16* __restrict__ Q, const u16* __restrict__ Kk,
            const u16* __restrict__ Vt, u16* __restrict__ AO)
{
  __shared__ u16 kvS[32768];       // 64 KB: K[512][64], then V^T[64][512]
  __shared__ u16 Pt[4][2048];      // 16 KB: per-wave P^T chunk [128k][16q]
  int bid = blockIdx.x;
  int bh = (bid & 7) * 32 + (bid >> 6);      // all 8 q-tiles of a bh -> one XCD
  int qt = (bid >> 3) & 7;
  int t = threadIdx.x, lane = t & 63, w = t >> 6;
  const u16* Kb = Kk + (size_t)bh * (NSEQ * HDIM);
  const u16* Vb = Vt + (size_t)bh * (HDIM * NSEQ);
  int r0 = lane & 15, hi = lane >> 4, kk0 = hi * 8;

  int qrow = qt * 64 + w * 16 + r0;
  const u16* Qp = Q + ((size_t)bh * NSEQ + qrow) * HDIM;
  bf16x8 qf0 = *(const bf16x8*)(Qp + kk0);
  bf16x8 qf1 = *(const bf16x8*)(Qp + 32 + kk0);

  const f32x4 vzero = {0.f, 0.f, 0.f, 0.f};
  f32x4 accS[32];
#pragma unroll
  for (int f = 0; f < 32; ++f) accS[f] = vzero;

  // ---- stage ALL of K (4 x 16KB), one barrier ----
#pragma unroll
  for (int i = 0; i < 4; ++i)
    stage16k<128>(Kb + (size_t)i * 128 * HDIM, HDIM, kvS + i * 8192);
  __syncthreads();

  // ---- S = Q K^T, barrier-free ----
  const char* smK = (const char*)kvS;
#pragma unroll
  for (int kf = 0; kf < 32; ++kf) {
    int krow = kf * 16 + r0;
    int swz = (krow & 7) << 4;
    bf16x8 b0 = *(const bf16x8*)(smK + krow * 128 + (((kk0)      * 2) ^ swz));
    bf16x8 b1 = *(const bf16x8*)(smK + krow * 128 + (((32 + kk0) * 2) ^ swz));
    accS[kf] = __builtin_amdgcn_mfma_f32_16x16x32_bf16(qf0, b0, accS[kf], 0, 0, 0);
    accS[kf] = __builtin_amdgcn_mfma_f32_16x16x32_bf16(qf1, b1, accS[kf], 0, 0, 0);
  }
  __syncthreads();                 // all waves done reading K

  // ---- stage ALL of V^T (overwrites K region); softmax hides the latency --
#pragma unroll
  for (int i = 0; i < 4; ++i)
    stage16k<1024>(Vb + (size_t)i * 16 * NSEQ, NSEQ, kvS + i * 8192);

  float mx[4], den[4], rden[4];
#pragma unroll
  for (int j = 0; j < 4; ++j) {
    float m = -1e30f;
#pragma unroll
    for (int f = 0; f < 32; ++f) m = fmaxf(m, accS[f][j]);
    m = fmaxf(m, __shfl_xor(m, 1));
    m = fmaxf(m, __shfl_xor(m, 2));
    m = fmaxf(m, __shfl_xor(m, 4));
    m = fmaxf(m, __shfl_xor(m, 8));
    mx[j] = m;
    den[j] = 0.f;
  }
  uint32_t pb[64];
#pragma unroll
  for (int f = 0; f < 32; ++f) {
    float p0 = __expf((accS[f][0] - mx[0]) * 0.03125f);
    float p1 = __expf((accS[f][1] - mx[1]) * 0.03125f);
    float p2 = __expf((accS[f][2] - mx[2]) * 0.03125f);
    float p3 = __expf((accS[f][3] - mx[3]) * 0.03125f);
    den[0] += p0; den[1] += p1; den[2] += p2; den[3] += p3;
    pb[f * 2 + 0] = (uint32_t)f2bf(p0) | ((uint32_t)f2bf(p1) << 16);
    pb[f * 2 + 1] = (uint32_t)f2bf(p2) | ((uint32_t)f2bf(p3) << 16);
  }
#pragma unroll
  for (int j = 0; j < 4; ++j) {
    float d = den[j];
    d += __shfl_xor(d, 1); d += __shfl_xor(d, 2);
    d += __shfl_xor(d, 4); d += __shfl_xor(d, 8);
    rden[j] = 1.0f / d;
  }
  __syncthreads();                 // V^T staged (barrier drains vmcnt)

  // ---- O = P V, fully wave-private (no barriers) ----
  int perm0 = ((r0 & 4) << 2) + ((r0 >> 3) << 2) + (r0 & 3);
  uint32_t ptb = (uint32_t)(uintptr_t)(as3_u16p)&Pt[w][0];
  uint32_t trBase = ptb + r0 * 2 + hi * 128;
  char* PtW = (char*)&Pt[w][0];
  const char* smV = (const char*)kvS;

  f32x4 accO[4];
#pragma unroll
  for (int nf = 0; nf < 4; ++nf) accO[nf] = vzero;

#pragma unroll
  for (int kt = 0; kt < 4; ++kt) {
#pragma unroll
    for (int fl = 0; fl < 8; ++fl) {
      int f = kt * 8 + fl;
      int row = (fl >> 1) * 32 + perm0 + ((fl & 1) << 3);
      *(uint2*)(PtW + row * 32 + hi * 8) = make_uint2(pb[f * 2], pb[f * 2 + 1]);
    }
    asm volatile("s_waitcnt lgkmcnt(0)" ::: "memory");
    __builtin_amdgcn_sched_barrier(0);
#pragma unroll
    for (int s = 0; s < 4; ++s) {
      uint2 t0, t1;
      uint32_t a0 = trBase + s * 1024;
      asm volatile("ds_read_b64_tr_b16 %0, %1" : "=v"(t0) : "v"(a0) : "memory");
      asm volatile("ds_read_b64_tr_b16 %0, %1" : "=v"(t1) : "v"(a0 + 512) : "memory");
      bf16x8 vb[4];
      int kkv = kt * 128 + s * 32 + kk0;
#pragma unroll
      for (int nf = 0; nf < 4; ++nf) {
        int d = nf * 16 + r0;
        vb[nf] = *(const bf16x8*)(smV + d * 1024 + ((kkv * 2) ^ ((d & 7) << 4)));
      }
      asm volatile("s_waitcnt lgkmcnt(0)" ::: "memory");
      __builtin_amdgcn_sched_barrier(0);
      union { uint4 u; bf16x8 v; } pa;
      pa.u = make_uint4(t0.x, t0.y, t1.x, t1.y);
#pragma unroll
      for (int nf = 0; nf < 4; ++nf)
        accO[nf] = __builtin_amdgcn_mfma_f32_16x16x32_bf16(pa.v, vb[nf], accO[nf], 0, 0, 0);
    }
  }

  int b_ = bh >> 4, hh = bh & 15;
#pragma unroll
  for (int nf = 0; nf < 4; ++nf)
#pragma unroll
    for (int j = 0; j < 4; ++j) {
      int ql = hi * 4 + j;
      int tok = qt * 64 + w * 16 + ql;
      int col = hh * 64 + nf * 16 + r0;
      AO[((size_t)(b_ * NSEQ + tok)) * EMB + col] = f2bf(accO[nf][j] * rden[j]);
    }
}

// ---------------- launch ---------------------------------------------------
extern "C" void kernel_launch(void* const* d_in, const int* in_sizes, int n_in,
                              void* d_out, int out_size, void* d_ws, size_t ws_size,
                              hipStream_t stream)
{
  const float* x    = (const float*)d_in[0];
  const float* cls  = (const float*)d_in[1];
  const float* pos  = (const float*)d_in[2];
  const float* Wq   = (const float*)d_in[3];
  const float* Wk   = (const float*)d_in[4];
  const float* Wv   = (const float*)d_in[5];
  const float* Wp   = (const float*)d_in[6];
  const float* ln1g = (const float*)d_in[7];
  const float* ln1b = (const float*)d_in[8];
  const float* ln2g = (const float*)d_in[9];
  const float* ln2b = (const float*)d_in[10];
  const float* W1   = (const float*)d_in[11];
  const float* b1   = (const float*)d_in[12];
  const float* W2   = (const float*)d_in[13];
  const float* b2   = (const float*)d_in[14];
  float* H = (float*)d_out;          // residual stream lives in d_out (fp32)

  char* ws = (char*)d_ws;            // 160 MiB used
  u16* wqkv = (u16*)(ws + 0);                // [6][3072][1024] bf16 (B^T)
  u16* wp   = (u16*)(ws + 37748736);         // [6][1024][1024]
  u16* w1t  = (u16*)(ws + 50331648);         // [6][2048][1024]
  u16* w2t  = (u16*)(ws + 75497472);         // [6][1024][2048]
  u16* xn   = (u16*)(ws + 100663296);        // [8192][1024] (also attn out)
  u16* qb   = (u16*)(ws + 117440512);        // [256][512][64]
  u16* kb   = (u16*)(ws + 134217728);        // [256][512][64]
  u16* vtb  = (u16*)(ws + 150994944);        // [256][64][512]
  u16* ffb  = qb;                            // [8192][2048] aliases q+k

  wprep_k<<<1536, 256, 0, stream>>>(Wq, wqkv, 1024, 1024, 1048576, 3145728, 0);
  wprep_k<<<1536, 256, 0, stream>>>(Wk, wqkv, 1024, 1024, 1048576, 3145728, 1048576);
  wprep_k<<<1536, 256, 0, stream>>>(Wv, wqkv, 1024, 1024, 1048576, 3145728, 2097152);
  wprep_k<<<1536, 256, 0, stream>>>(Wp, wp,   1024, 1024, 1048576, 1048576, 0);
  wprep_k<<<3072, 256, 0, stream>>>(W1, w1t,  1024, 2048, 2097152, 2097152, 0);
  wprep_k<<<3072, 256, 0, stream>>>(W2, w2t,  2048, 1024, 2097152, 2097152, 0);

  embed_k<<<NTOK, 256, 0, stream>>>(x, cls, pos, H);

  for (int l = 0; l < DEPTH; ++l) {
    ln_k<<<NTOK, 256, 0, stream>>>(H, ln1g + l * EMB, ln1b + l * EMB, xn);
    gemm_k<0><<<64 * 24, 256, 0, stream>>>(xn, wqkv + (size_t)l * 3145728, 24, 1024,
                                           nullptr, nullptr, nullptr, qb, kb, vtb);
    attn_k<<<2048, 256, 0, stream>>>(qb, kb, vtb, xn);
    gemm_k<1><<<64 * 8, 256, 0, stream>>>(xn, wp + (size_t)l * 1048576, 8, 1024,
                                          nullptr, H, nullptr, nullptr, nullptr, nullptr);
    ln_k<<<NTOK, 256, 0, stream>>>(H, ln2g + l * EMB, ln2b + l * EMB, xn);
    gemm_k<2><<<64 * 16, 256, 0, stream>>>(xn, w1t + (size_t)l * 2097152, 16, 1024,
                                           b1 + l * FFD, nullptr, ffb, nullptr, nullptr, nullptr);
    gemm_k<3><<<64 * 8, 256, 0, stream>>>(ffb, w2t + (size_t)l * 2097152, 8, 2048,
                                          b2 + l * EMB, H, nullptr, nullptr, nullptr, nullptr);
  }
}

// Round 7
// 1453.449 us; speedup vs baseline: 1.1099x; 1.0489x over previous
//
#include <hip/hip_runtime.h>
#include <cstdint>
#include <cstddef>

#define DEPTH 6
#define NB    16
#define NSEQ  512
#define EMB   1024
#define NHEAD 16
#define HDIM  64
#define FFD   2048
#define NTOK  (NB * NSEQ)   // 8192

typedef unsigned short u16;
using bf16x8 = __attribute__((ext_vector_type(8))) __bf16;
using f32x4  = __attribute__((ext_vector_type(4))) float;
using f32x16 = __attribute__((ext_vector_type(16))) float;
using u16x4  = __attribute__((ext_vector_type(4))) u16;
using u16x8  = __attribute__((ext_vector_type(8))) u16;

typedef __attribute__((address_space(1))) uint32_t* as1_u32p;
typedef __attribute__((address_space(3))) uint32_t* as3_u32p;

__device__ __forceinline__ u16 f2bf(float f) {
  union { float f; uint32_t u; } v; v.f = f;
  uint32_t u = v.u;
  return (u16)((u + 0x7FFFu + ((u >> 16) & 1u)) >> 16);
}

__device__ __forceinline__ void gload_lds16(const u16* g, u16* l) {
  void* gp = const_cast<u16*>(g);
  __builtin_amdgcn_global_load_lds((as1_u32p)gp, (as3_u32p)l, 16, 0, 0);
}

// Stage a 16KB tile (rows of ROWBYTES bytes) global->LDS, linear LDS dest,
// XOR-swizzled global source so that reads with byte^((row&7)<<4) are
// bank-conflict-free (rule #21). 256-thread version.
template<int ROWBYTES>
__device__ __forceinline__ void stage16k(const u16* g0, int ldk, u16* lds) {
  int t = threadIdx.x;
#pragma unroll
  for (int i = 0; i < 4; ++i) {
    int off = (i * 256 + t) * 16;          // LDS byte offset
    int row = off / ROWBYTES;
    int pc  = (off % ROWBYTES) >> 4;
    int lc  = pc ^ (row & 7);
    gload_lds16(g0 + (size_t)row * ldk + lc * 8, lds + (off >> 1));
  }
}

// ---------------- weight prep: fp32 [K][N] -> bf16 [N][K] (B^T layout) ----
__global__ __launch_bounds__(256)
void wprep_k(const float* __restrict__ W, u16* __restrict__ Wt,
             int K, int N, size_t inL, size_t outL, size_t outOff)
{
  int ntiles = N >> 6, ktiles = K >> 6;
  int bid = blockIdx.x;
  int l = bid / (ktiles * ntiles);
  int r = bid % (ktiles * ntiles);
  int kt = r / ntiles, nt = r % ntiles;
  const float* in = W + (size_t)l * inL + (size_t)(kt * 64) * N + nt * 64;
  u16* out = Wt + (size_t)l * outL + outOff + (size_t)(nt * 64) * K + kt * 64;
  __shared__ float tile[64][65];
  int t = threadIdx.x;
  int tr = t >> 4, tc = (t & 15) * 4;
#pragma unroll
  for (int i = 0; i < 4; ++i) {
    f32x4 v = *(const f32x4*)(in + (size_t)(tr + i * 16) * N + tc);
    tile[tr + i * 16][tc + 0] = v[0];
    tile[tr + i * 16][tc + 1] = v[1];
    tile[tr + i * 16][tc + 2] = v[2];
    tile[tr + i * 16][tc + 3] = v[3];
  }
  __syncthreads();
#pragma unroll
  for (int i = 0; i < 4; ++i) {
    int nr = tr + i * 16;
    u16x4 o;
    o[0] = f2bf(tile[tc + 0][nr]);
    o[1] = f2bf(tile[tc + 1][nr]);
    o[2] = f2bf(tile[tc + 2][nr]);
    o[3] = f2bf(tile[tc + 3][nr]);
    *(u16x4*)(out + (size_t)nr * K + tc) = o;
  }
}

// ---------------- embed: concat cls + pos add ------------------------------
__global__ __launch_bounds__(256)
void embed_k(const float* __restrict__ x, const float* __restrict__ cls,
             const float* __restrict__ pos, float* __restrict__ H)
{
  int row = blockIdx.x, t = threadIdx.x;
  int b_ = row >> 9, n = row & 511;
  int c = t * 4;
  f32x4 p = *(const f32x4*)(pos + (size_t)n * EMB + c);
  f32x4 s;
  if (n == 0) s = *(const f32x4*)(cls + c);
  else        s = *(const f32x4*)(x + ((size_t)b_ * 511 + (n - 1)) * EMB + c);
  f32x4 o = s + p;
  *(f32x4*)(H + (size_t)row * EMB + c) = o;
}

// ---------------- layernorm: fp32 h -> bf16 xn ----------------------------
__global__ __launch_bounds__(256)
void ln_k(const float* __restrict__ H, const float* __restrict__ g,
          const float* __restrict__ b, u16* __restrict__ out)
{
  int row = blockIdx.x, t = threadIdx.x;
  const float* hp = H + (size_t)row * EMB;
  f32x4 v = *(const f32x4*)(hp + t * 4);
  float s  = v[0] + v[1] + v[2] + v[3];
  float ss = v[0]*v[0] + v[1]*v[1] + v[2]*v[2] + v[3]*v[3];
#pragma unroll
  for (int m = 1; m <= 32; m <<= 1) { s += __shfl_xor(s, m); ss += __shfl_xor(ss, m); }
  __shared__ float red[8];
  if ((t & 63) == 0) { red[(t >> 6) * 2] = s; red[(t >> 6) * 2 + 1] = ss; }
  __syncthreads();
  float S  = red[0] + red[2] + red[4] + red[6];
  float SS = red[1] + red[3] + red[5] + red[7];
  float mean = S * (1.0f / EMB);
  float var  = SS * (1.0f / EMB) - mean * mean;
  float rs = rsqrtf(var + 1e-5f);
  f32x4 gg = *(const f32x4*)(g + t * 4);
  f32x4 bb = *(const f32x4*)(b + t * 4);
  u16x4 o;
#pragma unroll
  for (int i = 0; i < 4; ++i) o[i] = f2bf((v[i] - mean) * rs * gg[i] + bb[i]);
  *(u16x4*)(out + (size_t)row * EMB + t * 4) = o;
}

// ================= 128x128 GEMM, m97-exact single-buffer (32KB LDS) =======
// EPI: 0=QKV scatter via LDS-coalesced epi  1=+resid->H(f32)
//      2=+bias,gelu->outB via LDS epi       3=+bias+resid->H(f32)
template<int EPI>
__global__ __launch_bounds__(256, 3)
void gemm_k(const u16* __restrict__ A, const u16* __restrict__ Bt,
            int nbn, int K,
            const float* __restrict__ bias, float* __restrict__ H,
            u16* __restrict__ outB,
            u16* __restrict__ qo, u16* __restrict__ ko, u16* __restrict__ vto)
{
  __shared__ u16 sm[16384];            // 32 KB: A tile | B tile; reused by epi
  int cpx = gridDim.x >> 3;
  int logical = (blockIdx.x & 7) * cpx + (blockIdx.x >> 3);
  int bm = logical / nbn, bn = logical % nbn;
  int t = threadIdx.x, lane = t & 63, w = t >> 6;
  int wm = w >> 1, wn = w & 1;
  const u16* Ab = A  + (size_t)(bm * 128) * K;
  const u16* Bb = Bt + (size_t)(bn * 128) * K;
  int nkt = K >> 6;

  const f32x4 vzero = {0.f, 0.f, 0.f, 0.f};
  f32x4 acc[4][4];
#pragma unroll
  for (int i = 0; i < 4; ++i)
#pragma unroll
    for (int j = 0; j < 4; ++j) acc[i][j] = vzero;

  int r0 = lane & 15;
  int hi = lane >> 4;
  int kk0 = hi * 8;

  for (int kt = 0; kt < nkt; ++kt) {
    stage16k<128>(Ab + kt * 64, K, sm);
    stage16k<128>(Bb + kt * 64, K, sm + 8192);
    __syncthreads();                    // drains vmcnt: tile ready
    const char* smAp = (const char*)sm;
    const char* smBp = (const char*)(sm + 8192);
#pragma unroll
    for (int ks = 0; ks < 2; ++ks) {
      int kk = ks * 32 + kk0;
      bf16x8 a[4], b[4];
#pragma unroll
      for (int mf = 0; mf < 4; ++mf) {
        int row = wm * 64 + mf * 16 + r0;
        a[mf] = *(const bf16x8*)(smAp + row * 128 + ((kk * 2) ^ ((row & 7) << 4)));
      }
#pragma unroll
      for (int nf = 0; nf < 4; ++nf) {
        int row = wn * 64 + nf * 16 + r0;
        b[nf] = *(const bf16x8*)(smBp + row * 128 + ((kk * 2) ^ ((row & 7) << 4)));
      }
#pragma unroll
      for (int mf = 0; mf < 4; ++mf)
#pragma unroll
        for (int nf = 0; nf < 4; ++nf)
          acc[mf][nf] = __builtin_amdgcn_mfma_f32_16x16x32_bf16(a[mf], b[nf], acc[mf][nf], 0, 0, 0);
    }
    __syncthreads();                    // readers done; next stage may overwrite
  }

  if (EPI == 1 || EPI == 3) {
    int m0 = bm * 128 + wm * 64;
    int n0 = bn * 128 + wn * 64;
#pragma unroll
    for (int mf = 0; mf < 4; ++mf) {
#pragma unroll
      for (int nf = 0; nf < 4; ++nf) {
        int col  = n0 + nf * 16 + r0;
        int rowb = m0 + mf * 16 + hi * 4;
#pragma unroll
        for (int j = 0; j < 4; ++j) {
          float v = acc[mf][nf][j];
          size_t idx = (size_t)(rowb + j) * EMB + col;
          if (EPI == 1) H[idx] = v + H[idx];
          else          H[idx] = v + bias[col] + H[idx];
        }
      }
    }
    return;
  }

  // ---- LDS-coalesced epilogue (EPI 0 / 2) --------------------------------
  int sec = (bn * 128) >> 10;           // EPI0: 0=q 1=k 2=v ; EPI2: always 0/1
  bool vsec = (EPI == 0) && (sec == 2);
#pragma unroll
  for (int mf = 0; mf < 4; ++mf) {
#pragma unroll
    for (int nf = 0; nf < 4; ++nf) {
      int colL = wn * 64 + nf * 16 + r0;
#pragma unroll
      for (int j = 0; j < 4; ++j) {
        int rowL = wm * 64 + mf * 16 + hi * 4 + j;
        float v = acc[mf][nf][j];
        if (EPI == 2) {
          float xg = v + bias[bn * 128 + colL];
          v = 0.5f * xg * (1.0f + erff(xg * 0.70710678118654752f));
        }
        u16 o = f2bf(v);
        if (!vsec)
          sm[rowL * 128 + (colL & 7) + ((((colL >> 3) ^ (rowL & 7))) << 3)] = o;
        else  // v: store transposed [c][n]
          sm[colL * 128 + (rowL & 7) + ((((rowL >> 3) ^ (colL & 7))) << 3)] = o;
      }
    }
  }
  __syncthreads();

  int c  = t & 15;                      // chunk of 8 cols
  int rb = t >> 4;
  if (!vsec) {
#pragma unroll
    for (int i = 0; i < 8; ++i) {
      int row = rb * 8 + i;
      u16x8 v = *(const u16x8*)(sm + row * 128 + ((c ^ (row & 7)) << 3));
      if (EPI == 2) {
        int rowg = bm * 128 + row;
        int colg = bn * 128 + c * 8;
        *(u16x8*)(outB + (size_t)rowg * FFD + colg) = v;
      } else {
        int n_ = bm * 128 + row;
        int b_ = n_ >> 9, tok = n_ & 511;
        int c0 = (bn * 128 - sec * 1024) + c * 8;
        int hh = c0 >> 6, d0 = c0 & 63;
        u16* dst = (sec == 0) ? qo : ko;
        *(u16x8*)(dst + (((size_t)(b_ * NHEAD + hh) * NSEQ + tok) * HDIM) + d0) = v;
      }
    }
  } else {
#pragma unroll
    for (int i = 0; i < 8; ++i) {
      int rowp = rb * 8 + i;            // local c (head*64+d)
      u16x8 v = *(const u16x8*)(sm + rowp * 128 + ((c ^ (rowp & 7)) << 3));
      int c0 = (bn * 128 - 2048) + rowp;
      int hh = c0 >> 6, d = c0 & 63;
      int tok0 = bm * 128 + c * 8;
      int b_ = tok0 >> 9;
      *(u16x8*)(vto + ((size_t)(b_ * NHEAD + hh) * HDIM + d) * NSEQ + (tok0 & 511)) = v;
    }
  }
}

// ============== fused attention: swapped-QK^T 32x32, online softmax ========
// 4 waves x 32 q-rows = 128 q per block; KV in 128-key chunks, dbuf.
// S = mfma32(K,Q): lane holds S[q=lane&31][keys in regs] -> in-lane softmax,
// cvt_pk + permlane32_swap builds PV A-frags in-register (no P LDS).
__global__ __launch_bounds__(256, 2)
void attn_k(const u16* __restrict__ Q, const u16* __restrict__ Kk,
            const u16* __restrict__ Vt, u16* __restrict__ AO)
{
  __shared__ u16 bufK[2][8192];    // 16KB chunk: K[128 keys][64 d]
  __shared__ u16 bufV[2][8192];    // 16KB chunk: V^T[64 d][128 keys]
  int bid = blockIdx.x;
  int logical = (bid & 7) * 128 + (bid >> 3);   // XCD swizzle (1024 blocks)
  int bh = logical >> 2, qt = logical & 3;
  int t = threadIdx.x, lane = t & 63, w = t >> 6;
  int l31 = lane & 31, hi32 = lane >> 5;
  const u16* Kb = Kk + (size_t)bh * (NSEQ * HDIM);
  const u16* Vb = Vt + (size_t)bh * (HDIM * NSEQ);

  // Q B-fragments: lane l31 -> q-row, k = 16*tk + 8*hi32 + e
  int qbase = qt * 128 + w * 32;
  const u16* Qp = Q + ((size_t)bh * NSEQ + qbase + l31) * HDIM;
  bf16x8 qf[4];
#pragma unroll
  for (int tk = 0; tk < 4; ++tk)
    qf[tk] = *(const bf16x8*)(Qp + 16 * tk + 8 * hi32);

  stage16k<128>(Kb, HDIM, &bufK[0][0]);
  stage16k<256>(Vb, NSEQ, &bufV[0][0]);
  __syncthreads();

  f32x16 accO[2];
#pragma unroll
  for (int r = 0; r < 16; ++r) { accO[0][r] = 0.f; accO[1][r] = 0.f; }
  float m_run = -1e30f, den = 0.f;
  const float inv32 = 0.03125f;      // 1/sqrt(EMB)

  for (int c = 0; c < 4; ++c) {
    if (c < 3) {
      stage16k<128>(Kb + (size_t)(c + 1) * 128 * HDIM, HDIM, &bufK[(c + 1) & 1][0]);
      stage16k<256>(Vb + (c + 1) * 128, NSEQ, &bufV[(c + 1) & 1][0]);
    }
    // ---- S chunk: 4 key-tiles x 4 k-steps of mfma32(K, Q) ----
    const char* smK = (const char*)&bufK[c & 1][0];
    f32x16 s[4];
#pragma unroll
    for (int kt = 0; kt < 4; ++kt) {
#pragma unroll
      for (int r = 0; r < 16; ++r) s[kt][r] = 0.f;
#pragma unroll
      for (int tk = 0; tk < 4; ++tk) {
        int row = kt * 32 + l31;
        bf16x8 kf = *(const bf16x8*)(smK + row * 128 +
                      ((32 * tk + 16 * hi32) ^ ((row & 7) << 4)));
        s[kt] = __builtin_amdgcn_mfma_f32_32x32x16_bf16(kf, qf[tk], s[kt], 0, 0, 0);
      }
    }
    // ---- online softmax (row = in-lane + xor32 partner) ----
    float mc = -1e30f;
#pragma unroll
    for (int kt = 0; kt < 4; ++kt)
#pragma unroll
      for (int r = 0; r < 16; ++r) mc = fmaxf(mc, s[kt][r]);
    mc = fmaxf(mc, __shfl_xor(mc, 32));
    float newm = fmaxf(m_run, mc);
    float fac = __expf((m_run - newm) * inv32);
    den *= fac;
#pragma unroll
    for (int r = 0; r < 16; ++r) { accO[0][r] *= fac; accO[1][r] *= fac; }
    m_run = newm;
#pragma unroll
    for (int kt = 0; kt < 4; ++kt)
#pragma unroll
      for (int r = 0; r < 16; ++r) {
        float p = __expf((s[kt][r] - newm) * inv32);
        den += p;
        s[kt][r] = p;
      }
    // pack P to bf16 pairs: pb[j] = {p[2j] lo, p[2j+1] hi}
    uint32_t pb[32];
#pragma unroll
    for (int j = 0; j < 32; ++j) {
      float lo = s[j >> 3][(2 * j) & 15];
      float hi = s[j >> 3][((2 * j) & 15) + 1];
      asm("v_cvt_pk_bf16_f32 %0, %1, %2" : "=v"(pb[j]) : "v"(lo), "v"(hi));
    }
    // ---- PV: per k-step build A-frag via 2 permlane32_swap ----
    const char* smV = (const char*)&bufV[c & 1][0];
#pragma unroll
    for (int ks = 0; ks < 8; ++ks) {
      uint32_t x0 = pb[4 * ks], y0 = pb[4 * ks + 2];
      uint32_t x1 = pb[4 * ks + 1], y1 = pb[4 * ks + 3];
      asm("v_permlane32_swap_b32 %0, %1" : "+v"(x0), "+v"(y0));
      asm("v_permlane32_swap_b32 %0, %1" : "+v"(x1), "+v"(y1));
      union { uint4 u; bf16x8 v; } pa;
      pa.u = make_uint4(x0, x1, y0, y1);
#pragma unroll
      for (int dt = 0; dt < 2; ++dt) {
        int row = dt * 32 + l31;
        bf16x8 vb = *(const bf16x8*)(smV + row * 256 +
                      ((32 * ks + 16 * hi32) ^ ((row & 7) << 4)));
        accO[dt] = __builtin_amdgcn_mfma_f32_32x32x16_bf16(pa.v, vb, accO[dt], 0, 0, 0);
      }
    }
    __syncthreads();
  }

  // ---- epilogue: O[q][d], q=(r&3)+8*(r>>2)+4*hi32, d=l31+32*dt ----
  float denf = den + __shfl_xor(den, 32);
  float rden = 1.0f / denf;
  int b_ = bh >> 4, hh = bh & 15;
#pragma unroll
  for (int r = 0; r < 16; ++r) {
    int qoff = (r & 3) + 8 * (r >> 2) + 4 * hi32;
    float rd = __shfl(rden, qoff);
    int tok = qbase + qoff;
    size_t base = ((size_t)(b_ * NSEQ + tok)) * EMB + hh * 64 + l31;
    AO[base]      = f2bf(accO[0][r] * rd);
    AO[base + 32] = f2bf(accO[1][r] * rd);
  }
}

// ---------------- launch ---------------------------------------------------
extern "C" void kernel_launch(void* const* d_in, const int* in_sizes, int n_in,
                              void* d_out, int out_size, void* d_ws, size_t ws_size,
                              hipStream_t stream)
{
  const float* x    = (const float*)d_in[0];
  const float* cls  = (const float*)d_in[1];
  const float* pos  = (const float*)d_in[2];
  const float* Wq   = (const float*)d_in[3];
  const float* Wk   = (const float*)d_in[4];
  const float* Wv   = (const float*)d_in[5];
  const float* Wp   = (const float*)d_in[6];
  const float* ln1g = (const float*)d_in[7];
  const float* ln1b = (const float*)d_in[8];
  const float* ln2g = (const float*)d_in[9];
  const float* ln2b = (const float*)d_in[10];
  const float* W1   = (const float*)d_in[11];
  const float* b1   = (const float*)d_in[12];
  const float* W2   = (const float*)d_in[13];
  const float* b2   = (const float*)d_in[14];
  float* H = (float*)d_out;          // residual stream lives in d_out (fp32)

  char* ws = (char*)d_ws;            // 160 MiB used
  u16* wqkv = (u16*)(ws + 0);                // [6][3072][1024] bf16 (B^T)
  u16* wp   = (u16*)(ws + 37748736);         // [6][1024][1024]
  u16* w1t  = (u16*)(ws + 50331648);         // [6][2048][1024]
  u16* w2t  = (u16*)(ws + 75497472);         // [6][1024][2048]
  u16* xn   = (u16*)(ws + 100663296);        // [8192][1024] (also attn out)
  u16* qb   = (u16*)(ws + 117440512);        // [256][512][64]
  u16* kb   = (u16*)(ws + 134217728);        // [256][512][64]
  u16* vtb  = (u16*)(ws + 150994944);        // [256][64][512]
  u16* ffb  = qb;                            // [8192][2048] aliases q+k

  wprep_k<<<1536, 256, 0, stream>>>(Wq, wqkv, 1024, 1024, 1048576, 3145728, 0);
  wprep_k<<<1536, 256, 0, stream>>>(Wk, wqkv, 1024, 1024, 1048576, 3145728, 1048576);
  wprep_k<<<1536, 256, 0, stream>>>(Wv, wqkv, 1024, 1024, 1048576, 3145728, 2097152);
  wprep_k<<<1536, 256, 0, stream>>>(Wp, wp,   1024, 1024, 1048576, 1048576, 0);
  wprep_k<<<3072, 256, 0, stream>>>(W1, w1t,  1024, 2048, 2097152, 2097152, 0);
  wprep_k<<<3072, 256, 0, stream>>>(W2, w2t,  2048, 1024, 2097152, 2097152, 0);

  embed_k<<<NTOK, 256, 0, stream>>>(x, cls, pos, H);

  for (int l = 0; l < DEPTH; ++l) {
    ln_k<<<NTOK, 256, 0, stream>>>(H, ln1g + l * EMB, ln1b + l * EMB, xn);
    gemm_k<0><<<64 * 24, 256, 0, stream>>>(xn, wqkv + (size_t)l * 3145728, 24, 1024,
                                           nullptr, nullptr, nullptr, qb, kb, vtb);
    attn_k<<<1024, 256, 0, stream>>>(qb, kb, vtb, xn);
    gemm_k<1><<<64 * 8, 256, 0, stream>>>(xn, wp + (size_t)l * 1048576, 8, 1024,
                                          nullptr, H, nullptr, nullptr, nullptr, nullptr);
    ln_k<<<NTOK, 256, 0, stream>>>(H, ln2g + l * EMB, ln2b + l * EMB, xn);
    gemm_k<2><<<64 * 16, 256, 0, stream>>>(xn, w1t + (size_t)l * 2097152, 16, 1024,
                                           b1 + l * FFD, nullptr, ffb, nullptr, nullptr, nullptr);
    gemm_k<3><<<64 * 8, 256, 0, stream>>>(ffb, w2t + (size_t)l * 2097152, 8, 2048,
                                          b2 + l * EMB, H, nullptr, nullptr, nullptr, nullptr);
  }
}